// Round 2
// baseline (340.179 us; speedup 1.0000x reference)
//
#include <hip/hip_runtime.h>
#include <hip/hip_bf16.h>

// Eq4Net: permutation-equivariant 4th-order set network.
// T = x^{4} is rank-1 per channel -> layer-1 evaluated via closed-form tables;
// T1 (post-relu) materialized once in bf16; marginals derived hierarchically;
// all layer-2 marginal terms pre-contracted with coefs2 (tiny tables);
// final pass recombines + relu + pooled dot.

#define NB 4
#define NN 24
#define ND 16
#define NS 16
#define NO 16
#define NKL 576
#define TILE 9216  // NKL*NS

typedef unsigned int u32;
typedef unsigned short u16;

__device__ __forceinline__ u16 f2bf(float f) {
  u32 u = __float_as_uint(f);
  u = (u + 0x7fffu + ((u >> 16) & 1u)) >> 16;  // RNE
  return (u16)u;
}

// ---------------- K0: x = [relu(embed[xcat]) , xfeat], S = sum_i x ----------
__global__ __launch_bounds__(256) void k0_prep(
    const int* __restrict__ xcat, const float* __restrict__ xfeat,
    const float* __restrict__ embed, const float* __restrict__ b_out,
    float* __restrict__ xw, float* __restrict__ Sw, float* __restrict__ out) {
  __shared__ float sx[NB * NN * ND];
  const int t = threadIdx.x;
  for (int idx = t; idx < NB * NN * ND; idx += 256) {
    int d = idx & (ND - 1);
    int bi = idx >> 4;  // b*NN+i
    float v;
    if (d < 15) v = fmaxf(embed[xcat[bi] * 15 + d], 0.0f);
    else        v = xfeat[bi];
    sx[idx] = v;
    xw[idx] = v;
  }
  __syncthreads();
  for (int idx = t; idx < NB * ND; idx += 256) {
    int d = idx & (ND - 1), b = idx >> 4;
    float s = 0.0f;
    for (int i = 0; i < NN; ++i) s += sx[(b * NN + i) * ND + d];
    Sw[idx] = s;
  }
  if (t < NB) out[t] = b_out[0];
}

// ---------------- K2: layer 1 + relu -> T1 (bf16) + contracted m_k,m_l,mkl --
// block = (b,i,j); per element (k,l):
//   pre[s] = sum_d alpha[d,s]*x_k[d]*x_l[d] + Bt[k][s] + Gt[l][s] + dconst[s]
// Block-local marginals (sum over k / l / both) contracted with coefs2
// bases 3,4,10 in-block -> no raw m_k/m_l buffers needed downstream.
__global__ __launch_bounds__(192) void k2_layer1(
    const float* __restrict__ xw, const float* __restrict__ Sw,
    const float* __restrict__ coefs1, const float* __restrict__ bias1,
    const float* __restrict__ coefs2,
    u16* __restrict__ T1, float* __restrict__ mkc, float* __restrict__ mlc,
    float* __restrict__ mklc) {
  const int blk = blockIdx.x;
  const int j = blk % NN, i = (blk / NN) % NN, b = blk / (NN * NN);
  const int t = threadIdx.x;
  __shared__ __align__(16) float sx[NN * ND];
  __shared__ __align__(16) float alphaT[NS][ND];
  __shared__ float tb[ND][NS], tg[ND][NS], td[ND][NS];
  __shared__ float Bt[NN][20], Gt[NN][20];
  __shared__ float dconst[NS];
  __shared__ u32 T1p[NKL][9];              // packed bf16 tile (pad to 9 words)
  __shared__ float rk[NN][17], rl[NN][17]; // raw sum-over-k (keep l) / over-l
  __shared__ float rkl[NS];
  __shared__ float c2k[256], c2l[256], c2kl[256];

  const float* xb = xw + b * NN * ND;
  for (int idx = t; idx < NN * ND; idx += 192) sx[idx] = xb[idx];
  __syncthreads();

  for (int idx = t; idx < ND * NS; idx += 192) {
    int d = idx >> 4, s = idx & 15;
    const float* c = coefs1 + (d * NS + s) * 16;
    float xi = sx[i * ND + d], xj = sx[j * ND + d];
    float Sv = Sw[b * ND + d];
    float S2 = Sv * Sv, S3 = S2 * Sv, S4 = S2 * S2;
    float pij = xi * xj;
    alphaT[s][d] = c[0] * pij + c[1] * Sv * xj + c[2] * Sv * xi + c[5] * S2;
    tb[d][s] = c[4] * Sv * pij + c[9] * S2 * xi + c[7] * S2 * xj + c[12] * S3;
    tg[d][s] = c[3] * Sv * pij + c[8] * S2 * xi + c[6] * S2 * xj + c[11] * S3;
    td[d][s] = c[10] * S2 * pij + c[14] * S3 * xi + c[13] * S3 * xj + c[15] * S4;
  }
  __syncthreads();
  for (int idx = t; idx < NN * NS; idx += 192) {
    int k = idx >> 4, s = idx & 15;
    float sb = 0.f, sg = 0.f;
    for (int d = 0; d < ND; ++d) {
      float xv = sx[k * ND + d];
      sb += tb[d][s] * xv;
      sg += tg[d][s] * xv;
    }
    Bt[k][s] = sb;
    Gt[k][s] = sg;
  }
  if (t < NS) {
    float sd = 0.f;
    for (int d = 0; d < ND; ++d) sd += td[d][t];
    dconst[t] = sd + bias1[t];
  }
  for (int idx = t; idx < 256; idx += 192) {
    c2k[idx]  = coefs2[idx * 16 + 3];
    c2l[idx]  = coefs2[idx * 16 + 4];
    c2kl[idx] = coefs2[idx * 16 + 10];
  }
  __syncthreads();

  const int kl0 = t, kl1 = t + 192, kl2 = t + 384;  // 3*192 = 576 exact
  const int k0 = kl0 / NN, l0 = kl0 % NN;
  const int k1 = kl1 / NN, l1 = kl1 % NN;
  const int k2_ = kl2 / NN, l2 = kl2 % NN;

  float P0[ND], P1[ND], P2[ND];
#pragma unroll
  for (int d = 0; d < ND; ++d) {
    P0[d] = sx[k0 * ND + d] * sx[l0 * ND + d];
    P1[d] = sx[k1 * ND + d] * sx[l1 * ND + d];
    P2[d] = sx[k2_ * ND + d] * sx[l2 * ND + d];
  }
  float A0[NS], A1[NS], A2[NS];
#pragma unroll
  for (int s = 0; s < NS; ++s) {
    A0[s] = dconst[s] + Bt[k0][s] + Gt[l0][s];
    A1[s] = dconst[s] + Bt[k1][s] + Gt[l1][s];
    A2[s] = dconst[s] + Bt[k2_][s] + Gt[l2][s];
  }
#pragma unroll
  for (int s = 0; s < NS; ++s) {
    float a0 = A0[s], a1 = A1[s], a2 = A2[s];
#pragma unroll
    for (int d = 0; d < ND; ++d) {
      float av = alphaT[s][d];
      a0 += av * P0[d];
      a1 += av * P1[d];
      a2 += av * P2[d];
    }
    A0[s] = a0; A1[s] = a1; A2[s] = a2;
  }

  auto store_elem = [&](float (&A)[NS], int kl) {
    u32 w[8];
#pragma unroll
    for (int m = 0; m < 8; ++m) {
      float v0 = fmaxf(A[2 * m], 0.f);
      float v1 = fmaxf(A[2 * m + 1], 0.f);
      w[m] = (u32)f2bf(v0) | ((u32)f2bf(v1) << 16);
      T1p[kl][m] = w[m];
    }
    uint4* gp = (uint4*)(T1 + (size_t)blk * TILE + (size_t)kl * NS);
    gp[0] = make_uint4(w[0], w[1], w[2], w[3]);
    gp[1] = make_uint4(w[4], w[5], w[6], w[7]);
  };
  store_elem(A0, kl0);
  store_elem(A1, kl1);
  store_elem(A2, kl2);
  __syncthreads();

  // raw marginals from packed tile (bf16-rounded; tolerance is ~2% rel)
  for (int idx = t; idx < NN * NS; idx += 192) {
    int a = idx >> 4, s = idx & 15;
    int m = s >> 1;
    u32 odd = (u32)(s & 1);
    float sk = 0.f, sl = 0.f;
    for (int c = 0; c < NN; ++c) {
      u32 uk = T1p[c * NN + a][m];   // (k=c, l=a): sum over k
      u32 ul = T1p[a * NN + c][m];   // (k=a, l=c): sum over l
      sk += __uint_as_float(odd ? (uk & 0xffff0000u) : (uk << 16));
      sl += __uint_as_float(odd ? (ul & 0xffff0000u) : (ul << 16));
    }
    rk[a][s] = sk;
    rl[a][s] = sl;
  }
  __syncthreads();
  if (t < NS) {
    float v = 0.f;
    for (int a = 0; a < NN; ++a) v += rk[a][t];
    rkl[t] = v;
  }
  __syncthreads();

  // contract + write: rk->basis3 (m_k keeps l), rl->basis4, rkl->basis10
  for (int idx = t; idx < (2 * NN + 1) * NS; idx += 192) {
    int pos = idx >> 4, s2 = idx & 15;
    const float* raw; const float* cc; float* dst;
    if (pos < NN)           { raw = rk[pos];      cc = c2k;  dst = mkc  + ((size_t)blk * NN + pos) * NS + s2; }
    else if (pos < 2 * NN)  { raw = rl[pos - NN]; cc = c2l;  dst = mlc  + ((size_t)blk * NN + (pos - NN)) * NS + s2; }
    else                    { raw = rkl;          cc = c2kl; dst = mklc + (size_t)blk * NS + s2; }
    float o = 0.f;
#pragma unroll
    for (int s = 0; s < NS; ++s) o += cc[s * NS + s2] * raw[s];
    *dst = o;
  }
}

// ---------------- K3: raw m_i (sum over i), m_j (sum over j) from T1 --------
// 576 blocks x 192 thr; thread-per-(kl)-position, 24-term bf16 sum.
__global__ __launch_bounds__(192) void k3_margins(
    const u16* __restrict__ T1, float* __restrict__ m_i, float* __restrict__ m_j) {
  const int bid = blockIdx.x, t = threadIdx.x;
  const int grp = bid / 3, third = bid % 3;
  const int kl = third * 192 + t;
  int b, a; bool isI;
  if (grp < NB * NN) { isI = true;  b = grp / NN; a = grp % NN; }          // a = j
  else { isI = false; int g2 = grp - NB * NN; b = g2 / NN; a = g2 % NN; }  // a = i
  const u16* base; size_t stride;
  if (isI) { base = T1 + ((size_t)(b * NN) * NN + a) * TILE; stride = (size_t)NN * TILE; }
  else     { base = T1 + ((size_t)(b * NN + a) * NN) * TILE; stride = TILE; }
  float acc[16];
#pragma unroll
  for (int s = 0; s < 16; ++s) acc[s] = 0.f;
  for (int c = 0; c < NN; ++c) {
    const uint4* q = (const uint4*)(base + c * stride + (size_t)kl * NS);
    uint4 q0 = q[0], q1 = q[1];
    u32 qa[8] = {q0.x, q0.y, q0.z, q0.w, q1.x, q1.y, q1.z, q1.w};
#pragma unroll
    for (int m = 0; m < 8; ++m) {
      acc[2 * m]     += __uint_as_float(qa[m] << 16);
      acc[2 * m + 1] += __uint_as_float(qa[m] & 0xffff0000u);
    }
  }
  float* outp = (isI ? m_i : m_j) + ((size_t)(b * NN + a) * NKL + kl) * NS;
#pragma unroll
  for (int w = 0; w < 4; ++w)
    ((float4*)outp)[w] = make_float4(acc[4 * w], acc[4 * w + 1], acc[4 * w + 2], acc[4 * w + 3]);
}

// ---------------- K4: pairs/triples/quad directly from raw m_i/m_j,
//                  contracted with their coefs2 basis ------------------------
__global__ __launch_bounds__(256) void k4_small(
    const float* __restrict__ mi, const float* __restrict__ mj,
    const float* __restrict__ coefs2,
    float* __restrict__ mijc, float* __restrict__ mikc, float* __restrict__ milc,
    float* __restrict__ mjkc, float* __restrict__ mjlc,
    float* __restrict__ mijkc, float* __restrict__ mijlc,
    float* __restrict__ miklc, float* __restrict__ mjklc,
    float* __restrict__ mijklc) {
  __shared__ float c2[NS * NO * 16];  // 16 KB
  __shared__ float part[256];
  __shared__ float tot[16];
  const int t = threadIdx.x;
  for (int idx = t; idx < NS * NO * 16; idx += 256) c2[idx] = coefs2[idx];
  __syncthreads();
  const int blk = blockIdx.x;
  const int BREG = NN * NKL * NS;  // floats per b-slab of m_i/m_j (221184)

  if (blk < 45) {  // ---- pairs: 5 tables x 2304 positions, 24-term sums
    int pos = blk * 256 + t;
    int tbl = pos / 2304, r = pos % 2304;
    int b = r / 576, rem = r % 576;
    const float* p; int stride; int basis; float* dst;
    if (tbl == 0) {        // mij[b][kl] = sum_j m_i[b][j][kl]
      p = mi + ((size_t)b * NN * NKL + rem) * NS; stride = NKL * NS; basis = 5; dst = mijc;
    } else if (tbl == 1) { // mik[b][j][l] = sum_k m_i[b][j][k*NN+l]
      int jj = rem / NN, l = rem % NN;
      p = mi + (((size_t)b * NN + jj) * NKL + l) * NS; stride = NN * NS; basis = 6; dst = mikc;
    } else if (tbl == 2) { // mil[b][j][k] = sum_l m_i[b][j][k*NN+l]
      int jj = rem / NN, k = rem % NN;
      p = mi + (((size_t)b * NN + jj) * NKL + k * NN) * NS; stride = NS; basis = 7; dst = milc;
    } else if (tbl == 3) { // mjk[b][i][l] = sum_k m_j[b][i][k*NN+l]
      int ii = rem / NN, l = rem % NN;
      p = mj + (((size_t)b * NN + ii) * NKL + l) * NS; stride = NN * NS; basis = 8; dst = mjkc;
    } else {               // mjl[b][i][k] = sum_l m_j[b][i][k*NN+l]
      int ii = rem / NN, k = rem % NN;
      p = mj + (((size_t)b * NN + ii) * NKL + k * NN) * NS; stride = NS; basis = 9; dst = mjlc;
    }
    float raw[16];
#pragma unroll
    for (int s = 0; s < 16; ++s) raw[s] = 0.f;
    for (int x = 0; x < NN; ++x) {
      const float4* q = (const float4*)(p + (size_t)x * stride);
#pragma unroll
      for (int w = 0; w < 4; ++w) {
        float4 v = q[w];
        raw[4 * w] += v.x; raw[4 * w + 1] += v.y; raw[4 * w + 2] += v.z; raw[4 * w + 3] += v.w;
      }
    }
    float* op = dst + (size_t)r * NS;
#pragma unroll
    for (int s2 = 0; s2 < NO; ++s2) {
      float o = 0.f;
#pragma unroll
      for (int s = 0; s < NS; ++s) o += c2[(s * NO + s2) * 16 + basis] * raw[s];
      op[s2] = o;
    }
    return;
  }

  if (blk < 45 + 4 * NB * NN) {  // ---- triples: 576-term sums, block each
    int idx = blk - 45;
    int tbl = idx / (NB * NN), rem = idx % (NB * NN);
    int b = rem / NN, a = rem % NN;
    int s = t & 15, g = t >> 4;
    const float* base = (tbl == 3 ? mj : mi) + (size_t)b * BREG;
    float acc = 0.f;
    for (int tt = g; tt < NKL; tt += 16) {
      int pos;
      if (tbl == 0)      { int jj = tt / NN, k = tt % NN; pos = jj * NKL + k * NN + a; }  // keep l
      else if (tbl == 1) { int jj = tt / NN, l = tt % NN; pos = jj * NKL + a * NN + l; }  // keep k
      else               { pos = a * NKL + tt; }                                          // keep j / i
      acc += base[(size_t)pos * NS + s];
    }
    part[t] = acc;
    __syncthreads();
    if (t < 16) {
      float v = 0.f;
#pragma unroll
      for (int g2 = 0; g2 < 16; ++g2) v += part[g2 * 16 + t];
      tot[t] = v;
    }
    __syncthreads();
    if (t < 16) {
      int basis = 11 + tbl;
      float o = 0.f;
#pragma unroll
      for (int s_ = 0; s_ < NS; ++s_) o += c2[(s_ * NO + t) * 16 + basis] * tot[s_];
      float* dst = (tbl == 0 ? mijkc : tbl == 1 ? mijlc : tbl == 2 ? miklc : mjklc);
      dst[(size_t)(b * NN + a) * NS + t] = o;
    }
    return;
  }

  {  // ---- quad: 13824-term sum per b
    int b = blk - (45 + 4 * NB * NN);
    int s = t & 15, g = t >> 4;
    const float* base = mi + (size_t)b * BREG;
    float acc = 0.f;
    for (int v = g; v < NN * NKL; v += 16) acc += base[(size_t)v * NS + s];
    part[t] = acc;
    __syncthreads();
    if (t < 16) {
      float v = 0.f;
#pragma unroll
      for (int g2 = 0; g2 < 16; ++g2) v += part[g2 * 16 + t];
      tot[t] = v;
    }
    __syncthreads();
    if (t < 16) {
      float o = 0.f;
#pragma unroll
      for (int s_ = 0; s_ < NS; ++s_) o += c2[(s_ * NO + t) * 16 + 15] * tot[s_];
      mijklc[(size_t)b * NS + t] = o;
    }
  }
}

// ---------------- K4b: contract raw m_i (basis 1), m_j (basis 2) in place ---
__global__ __launch_bounds__(256) void k4b_big(
    float* __restrict__ mi, float* __restrict__ mj,
    const float* __restrict__ coefs2) {
  __shared__ float c2a[256], c2b[256];
  const int t = threadIdx.x;
  if (t < 256) {
    c2a[t] = coefs2[t * 16 + 1];
    c2b[t] = coefs2[t * 16 + 2];
  }
  __syncthreads();
  int pos = blockIdx.x * 256 + t;  // 110592 total, exact grid
  const int PBIG = NB * NN * NKL;  // 55296
  float* p; const float* cc;
  if (pos < PBIG) { p = mi + (size_t)pos * NS; cc = c2a; }
  else            { p = mj + (size_t)(pos - PBIG) * NS; cc = c2b; }
  float in[16];
#pragma unroll
  for (int w = 0; w < 4; ++w) {
    float4 v = ((const float4*)p)[w];
    in[4 * w] = v.x; in[4 * w + 1] = v.y; in[4 * w + 2] = v.z; in[4 * w + 3] = v.w;
  }
  float o[16];
#pragma unroll
  for (int s2 = 0; s2 < NO; ++s2) {
    float a = 0.f;
#pragma unroll
    for (int s = 0; s < NS; ++s) a += cc[s * NO + s2] * in[s];
    o[s2] = a;
  }
#pragma unroll
  for (int w = 0; w < 4; ++w)
    ((float4*)p)[w] = make_float4(o[4 * w], o[4 * w + 1], o[4 * w + 2], o[4 * w + 3]);
}

// ---------------- K5: layer 2 + relu + pool + w_out -------------------------
// One element per iteration (low VGPR -> more waves); XCD-swizzled blocks.
__global__ __launch_bounds__(192) void k5_layer2(
    const u16* __restrict__ T1,
    const float* __restrict__ mic, const float* __restrict__ mjc,
    const float* __restrict__ mkc, const float* __restrict__ mlc,
    const float* __restrict__ mijc, const float* __restrict__ mikc,
    const float* __restrict__ milc, const float* __restrict__ mjkc,
    const float* __restrict__ mjlc, const float* __restrict__ mklc,
    const float* __restrict__ mijkc, const float* __restrict__ mijlc,
    const float* __restrict__ miklc, const float* __restrict__ mjklc,
    const float* __restrict__ mijklc,
    const float* __restrict__ coefs2, const float* __restrict__ bias2,
    const float* __restrict__ w_out, float* __restrict__ out) {
  const int orig = blockIdx.x;
  const int blk = (orig & 7) * (NB * NN * NN / 8) + (orig >> 3);  // XCD swizzle
  const int j = blk % NN, i = (blk / NN) % NN, b = blk / (NN * NN);
  const int t = threadIdx.x;
  __shared__ __align__(16) float c2id[NS][NO];
  __shared__ float Kt[NN][20], Lt[NN][20];
  __shared__ float cterm[NO], wl[NO];
  __shared__ float wsum[3];

  for (int idx = t; idx < NS * NO; idx += 192)
    c2id[idx >> 4][idx & 15] = coefs2[idx * 16];  // basis 0
  for (int idx = t; idx < NN * NO; idx += 192) {
    int kk = idx >> 4, s2 = idx & 15;
    Kt[kk][s2] = mlc[(size_t)(((b * NN + i) * NN + j) * NN + kk) * NS + s2]
               + mjlc[(size_t)((b * NN + i) * NN + kk) * NS + s2]
               + milc[(size_t)((b * NN + j) * NN + kk) * NS + s2]
               + mijlc[(size_t)(b * NN + kk) * NS + s2];
    Lt[kk][s2] = mkc[(size_t)(((b * NN + i) * NN + j) * NN + kk) * NS + s2]
               + mjkc[(size_t)((b * NN + i) * NN + kk) * NS + s2]
               + mikc[(size_t)((b * NN + j) * NN + kk) * NS + s2]
               + mijkc[(size_t)(b * NN + kk) * NS + s2];
  }
  if (t < NO) {
    cterm[t] = mklc[(size_t)((b * NN + i) * NN + j) * NS + t]
             + miklc[(size_t)(b * NN + j) * NS + t]
             + mjklc[(size_t)(b * NN + i) * NS + t]
             + mijklc[(size_t)b * NS + t] + bias2[t];
    wl[t] = w_out[t];
  }
  __syncthreads();

  float p = 0.f;
#pragma unroll
  for (int it = 0; it < 3; ++it) {
    const int kl = t + 192 * it;
    const int k = kl / NN, l = kl % NN;
    const float4* pmi = (const float4*)(mic + ((size_t)(b * NN + j) * NKL + kl) * NS);
    const float4* pmj = (const float4*)(mjc + ((size_t)(b * NN + i) * NKL + kl) * NS);
    const float4* pms = (const float4*)(mijc + ((size_t)b * NKL + kl) * NS);
    const uint4* pt = (const uint4*)(T1 + (size_t)blk * TILE + (size_t)kl * NS);
    // issue all loads for this element together
    float4 a0 = pmi[0], a1 = pmi[1], a2 = pmi[2], a3 = pmi[3];
    float4 b0 = pmj[0], b1 = pmj[1], b2 = pmj[2], b3 = pmj[3];
    float4 g0 = pms[0], g1 = pms[1], g2 = pms[2], g3 = pms[3];
    uint4 q0 = pt[0], q1 = pt[1];
    float va[16], vb[16], vg[16];
    ((float4*)va)[0] = a0; ((float4*)va)[1] = a1; ((float4*)va)[2] = a2; ((float4*)va)[3] = a3;
    ((float4*)vb)[0] = b0; ((float4*)vb)[1] = b1; ((float4*)vb)[2] = b2; ((float4*)vb)[3] = b3;
    ((float4*)vg)[0] = g0; ((float4*)vg)[1] = g1; ((float4*)vg)[2] = g2; ((float4*)vg)[3] = g3;
    float acc[16];
#pragma unroll
    for (int s2 = 0; s2 < NO; ++s2)
      acc[s2] = cterm[s2] + Kt[k][s2] + Lt[l][s2] + va[s2] + vb[s2] + vg[s2];
    u32 qa[8] = {q0.x, q0.y, q0.z, q0.w, q1.x, q1.y, q1.z, q1.w};
#pragma unroll
    for (int m = 0; m < 8; ++m) {
      float lo = __uint_as_float(qa[m] << 16);
      float hi = __uint_as_float(qa[m] & 0xffff0000u);
#pragma unroll
      for (int s2 = 0; s2 < NO; ++s2)
        acc[s2] += c2id[2 * m][s2] * lo + c2id[2 * m + 1][s2] * hi;
    }
    float ps = 0.f;
#pragma unroll
    for (int s2 = 0; s2 < NO; ++s2) ps += wl[s2] * fmaxf(acc[s2], 0.f);
    p += ps;
  }
  for (int off = 32; off > 0; off >>= 1) p += __shfl_down(p, off, 64);
  if ((t & 63) == 0) wsum[t >> 6] = p;
  __syncthreads();
  if (t == 0) atomicAdd(&out[b], wsum[0] + wsum[1] + wsum[2]);
}

// ---------------- launch -----------------------------------------------------
extern "C" void kernel_launch(void* const* d_in, const int* in_sizes, int n_in,
                              void* d_out, int out_size, void* d_ws, size_t ws_size,
                              hipStream_t stream) {
  (void)in_sizes; (void)n_in; (void)out_size; (void)ws_size;
  const int*   xcat   = (const int*)d_in[0];
  const float* xfeat  = (const float*)d_in[1];
  const float* embed  = (const float*)d_in[2];
  const float* coefs1 = (const float*)d_in[3];
  const float* bias1  = (const float*)d_in[4];
  const float* coefs2 = (const float*)d_in[5];
  const float* bias2  = (const float*)d_in[6];
  const float* w_out  = (const float*)d_in[7];
  const float* b_out  = (const float*)d_in[8];
  float* out = (float*)d_out;
  char* ws = (char*)d_ws;

  float* xw    = (float*)(ws + 0);          // 6144 B
  float* Sw    = (float*)(ws + 6144);       // 256 B
  u16*   T1    = (u16*)(ws + 8192);         // 42467328 B
  float* m_i   = (float*)(ws + 42475520);   // 3538944 B (raw -> contracted in place)
  float* m_j   = (float*)(ws + 46014464);   // 3538944 B
  float* mkc   = (float*)(ws + 49553408);   // 3538944 B
  float* mlc   = (float*)(ws + 53092352);   // 3538944 B
  float* mijc  = (float*)(ws + 56631296);   // 147456 B
  float* mikc  = (float*)(ws + 56778752);
  float* milc  = (float*)(ws + 56926208);
  float* mjkc  = (float*)(ws + 57073664);
  float* mjlc  = (float*)(ws + 57221120);
  float* mklc  = (float*)(ws + 57368576);   // 147456 B
  float* mijkc = (float*)(ws + 57516032);   // 6144 B
  float* mijlc = (float*)(ws + 57522176);
  float* miklc = (float*)(ws + 57528320);
  float* mjklc = (float*)(ws + 57534464);
  float* mijklc= (float*)(ws + 57540608);   // 256 B

  k0_prep<<<1, 256, 0, stream>>>(xcat, xfeat, embed, b_out, xw, Sw, out);
  k2_layer1<<<NB * NN * NN, 192, 0, stream>>>(xw, Sw, coefs1, bias1, coefs2,
                                              T1, mkc, mlc, mklc);
  k3_margins<<<576, 192, 0, stream>>>(T1, m_i, m_j);
  k4_small<<<45 + 4 * NB * NN + NB, 256, 0, stream>>>(
      m_i, m_j, coefs2, mijc, mikc, milc, mjkc, mjlc,
      mijkc, mijlc, miklc, mjklc, mijklc);
  k4b_big<<<(2 * NB * NN * NKL) / 256, 256, 0, stream>>>(m_i, m_j, coefs2);
  k5_layer2<<<NB * NN * NN, 192, 0, stream>>>(
      T1, m_i, m_j, mkc, mlc, mijc, mikc, milc, mjkc, mjlc, mklc,
      mijkc, mijlc, miklc, mjklc, mijklc, coefs2, bias2, w_out, out);
}

// Round 3
// 324.507 us; speedup vs baseline: 1.0483x; 1.0483x over previous
//
#include <hip/hip_runtime.h>
#include <hip/hip_bf16.h>

// Eq4Net: permutation-equivariant 4th-order set network.
// Key idea: T = x^{otimes 4} is rank-1 per channel, so layer-1 pre-activations
// are pre[s](k,l) = sum_d alphaT[s][d]*x_k[d]*x_l[d] + Bt[k][s] + Gt[l][s] + dconst[s]
// with tables derived from coefs1 and S_d = sum_i x[b,i,d]. T1 = relu(pre) is
// NEVER materialized: each pass recomputes tiles in registers (~6 us VALU
// chip-wide per full evaluation). Layer-2 marginal terms are pre-contracted
// with coefs2 into small lookup tables; final pass recombines + relu + pool.

#define NB 4
#define NN 24
#define ND 16
#define NS 16
#define NO 16
#define NKL 576

typedef unsigned int u32;
typedef unsigned short u16;

__device__ __forceinline__ u16 f2bf(float f) {
  u32 u = __float_as_uint(f);
  u = (u + 0x7fffu + ((u >> 16) & 1u)) >> 16;  // RNE
  return (u16)u;
}

// ---------------- K0: x = [relu(embed[xcat]) , xfeat], S = sum_i x ----------
__global__ __launch_bounds__(256) void k0_prep(
    const int* __restrict__ xcat, const float* __restrict__ xfeat,
    const float* __restrict__ embed, const float* __restrict__ b_out,
    float* __restrict__ xw, float* __restrict__ Sw, float* __restrict__ out,
    float* __restrict__ quad_raw) {
  __shared__ float sx[NB * NN * ND];
  const int t = threadIdx.x;
  for (int idx = t; idx < NB * NN * ND; idx += 256) {
    int d = idx & (ND - 1);
    int bi = idx >> 4;
    float v;
    if (d < 15) v = fmaxf(embed[xcat[bi] * 15 + d], 0.0f);
    else        v = xfeat[bi];
    sx[idx] = v;
    xw[idx] = v;
  }
  __syncthreads();
  for (int idx = t; idx < NB * ND; idx += 256) {
    int d = idx & (ND - 1), b = idx >> 4;
    float s = 0.0f;
    for (int i = 0; i < NN; ++i) s += sx[(b * NN + i) * ND + d];
    Sw[idx] = s;
  }
  if (t < NB) out[t] = b_out[0];
  if (t < NB * NS) quad_raw[t] = 0.0f;
}

// ---------------- KA: marginal passes (recompute tiles, no T1) --------------
// blocks 0..383:   (b, j, ig): loop i in ig -> acc m_i[b][j] partial; also
//                  emit contracted mkc/mlc/mklc for each (b,i,j) tile.
// blocks 384..767: (b, i, jg): loop j in jg -> acc m_j[b][i] partial.
__global__ __launch_bounds__(192) void ka_marg(
    const float* __restrict__ xw, const float* __restrict__ Sw,
    const float* __restrict__ coefs1, const float* __restrict__ bias1,
    const float* __restrict__ coefs2,
    float* __restrict__ mi_part, float* __restrict__ mj_part,
    float* __restrict__ mkc, float* __restrict__ mlc, float* __restrict__ mklc) {
  const int bk = blockIdx.x;
  const bool isI = bk < 384;
  const int r = isI ? bk : bk - 384;
  const int b = r / 96;
  const int a = (r % 96) / 4;  // fixed index: j (isI) or i (!isI)
  const int g = r % 4;         // 6-wide group over the looped index
  const int t = threadIdx.x;

  __shared__ float sx[NN * ND];
  __shared__ float CT[16][256];            // per-b hoisted coefficient tables
  __shared__ float alphaT[NS][ND];
  __shared__ float tbs[ND][NS], tgs[ND][NS];
  __shared__ float Bt[NN][20], Gt[NN][20];
  __shared__ float dconst[NS];
  __shared__ u32 T1p[NKL][9];              // packed bf16 tile (isI only)
  __shared__ float rk[NN][17], rl[NN][17];
  __shared__ float rkl[NS];
  __shared__ float c2k[256], c2l[256], c2kl[256];

  const float* xb = xw + b * NN * ND;
  for (int idx = t; idx < NN * ND; idx += 192) sx[idx] = xb[idx];
  for (int idx = t; idx < 256; idx += 192) {
    const float* c = coefs1 + idx * 16;    // idx = d*16 + s
    int d = idx >> 4;
    float Sv = Sw[b * 16 + d];
    float S2 = Sv * Sv, S3 = S2 * Sv, S4 = S2 * S2;
    CT[0][idx] = c[0];        CT[1][idx] = c[1] * Sv;
    CT[2][idx] = c[2] * Sv;   CT[3][idx] = c[5] * S2;
    CT[4][idx] = c[4] * Sv;   CT[5][idx] = c[9] * S2;
    CT[6][idx] = c[7] * S2;   CT[7][idx] = c[12] * S3;
    CT[8][idx] = c[3] * Sv;   CT[9][idx] = c[8] * S2;
    CT[10][idx] = c[6] * S2;  CT[11][idx] = c[11] * S3;
    CT[12][idx] = c[10] * S2; CT[13][idx] = c[14] * S3;
    CT[14][idx] = c[13] * S3; CT[15][idx] = c[15] * S4;
    c2k[idx] = coefs2[idx * 16 + 3];
    c2l[idx] = coefs2[idx * 16 + 4];
    c2kl[idx] = coefs2[idx * 16 + 10];
  }
  __syncthreads();

  const int kl0 = t, kl1 = t + 192, kl2 = t + 384;
  const int k0 = kl0 / NN, l0 = kl0 % NN;
  const int k1 = kl1 / NN, l1 = kl1 % NN;
  const int k2 = kl2 / NN, l2 = kl2 % NN;

  float acc0[16], acc1[16], acc2[16];
#pragma unroll
  for (int s = 0; s < 16; ++s) { acc0[s] = 0.f; acc1[s] = 0.f; acc2[s] = 0.f; }

  for (int oo = g * 6; oo < g * 6 + 6; ++oo) {
    const int i = isI ? oo : a;
    const int j = isI ? a : oo;
    // per-(i,j) tables from hoisted per-b tables (3 FMA each)
    for (int idx = t; idx < 256; idx += 192) {
      int d = idx >> 4, s = idx & 15;
      float xi = sx[i * 16 + d], xj = sx[j * 16 + d], pij = xi * xj;
      alphaT[s][d] = CT[0][idx] * pij + CT[1][idx] * xj + CT[2][idx] * xi + CT[3][idx];
      tbs[d][s] = CT[4][idx] * pij + CT[5][idx] * xi + CT[6][idx] * xj + CT[7][idx];
      tgs[d][s] = CT[8][idx] * pij + CT[9][idx] * xi + CT[10][idx] * xj + CT[11][idx];
    }
    __syncthreads();
    for (int idx = t; idx < NN * NS; idx += 192) {
      int k = idx >> 4, s = idx & 15;
      float sb = 0.f, sg = 0.f;
      for (int d = 0; d < 16; ++d) {
        float xv = sx[k * 16 + d];
        sb += tbs[d][s] * xv;
        sg += tgs[d][s] * xv;
      }
      Bt[k][s] = sb;
      Gt[k][s] = sg;
    }
    if (t < 16) {
      float sd = 0.f;
      for (int d = 0; d < 16; ++d) {
        int idx = d * 16 + t;
        float xi = sx[i * 16 + d], xj = sx[j * 16 + d];
        sd += CT[12][idx] * xi * xj + CT[13][idx] * xi + CT[14][idx] * xj + CT[15][idx];
      }
      dconst[t] = sd + bias1[t];
    }
    __syncthreads();

    auto evalElem = [&](int kk, int ll, int kl, float (&acc)[16]) {
      float P[16];
#pragma unroll
      for (int d = 0; d < 16; ++d) P[d] = sx[kk * 16 + d] * sx[ll * 16 + d];
      float A[16];
#pragma unroll
      for (int s = 0; s < 16; ++s) A[s] = dconst[s] + Bt[kk][s] + Gt[ll][s];
#pragma unroll
      for (int s = 0; s < 16; ++s) {
        float av = A[s];
#pragma unroll
        for (int d = 0; d < 16; ++d) av += alphaT[s][d] * P[d];
        av = fmaxf(av, 0.f);
        A[s] = av;
        acc[s] += av;
      }
      if (isI) {
#pragma unroll
        for (int m = 0; m < 8; ++m)
          T1p[kl][m] = (u32)f2bf(A[2 * m]) | ((u32)f2bf(A[2 * m + 1]) << 16);
      }
    };
    evalElem(k0, l0, kl0, acc0);
    evalElem(k1, l1, kl1, acc1);
    evalElem(k2, l2, kl2, acc2);
    __syncthreads();

    if (isI) {  // row/col sums of this tile -> contracted mkc/mlc/mklc
      const int blkij = (b * NN + i) * NN + j;
      for (int idx = t; idx < NN * NS; idx += 192) {
        int aa = idx >> 4, s = idx & 15;
        int m = s >> 1;
        u32 odd = (u32)(s & 1);
        float sk = 0.f, sl = 0.f;
        for (int c = 0; c < NN; ++c) {
          u32 uk = T1p[c * NN + aa][m];   // sum over k, keep l=aa
          u32 ul = T1p[aa * NN + c][m];   // sum over l, keep k=aa
          sk += __uint_as_float(odd ? (uk & 0xffff0000u) : (uk << 16));
          sl += __uint_as_float(odd ? (ul & 0xffff0000u) : (ul << 16));
        }
        rk[aa][s] = sk;
        rl[aa][s] = sl;
      }
      __syncthreads();
      if (t < 16) {
        float v = 0.f;
        for (int aa = 0; aa < NN; ++aa) v += rk[aa][t];
        rkl[t] = v;
      }
      __syncthreads();
      for (int idx = t; idx < (2 * NN + 1) * NS; idx += 192) {
        int pos = idx >> 4, s2 = idx & 15;
        const float* raw; const float* cc; float* dst;
        if (pos < NN)          { raw = rk[pos];      cc = c2k;  dst = mkc + ((size_t)blkij * NN + pos) * NS + s2; }
        else if (pos < 2 * NN) { raw = rl[pos - NN]; cc = c2l;  dst = mlc + ((size_t)blkij * NN + (pos - NN)) * NS + s2; }
        else                   { raw = rkl;          cc = c2kl; dst = mklc + (size_t)blkij * NS + s2; }
        float o = 0.f;
#pragma unroll
        for (int s = 0; s < 16; ++s) o += cc[s * 16 + s2] * raw[s];
        *dst = o;
      }
    }
    __syncthreads();
  }

  // write m_i / m_j partial: part[g][(b*24+a)*576 + kl][s]
  float* dst = (isI ? mi_part : mj_part) + (size_t)g * 884736 +
               ((size_t)(b * NN + a) * NKL) * NS;
  auto wr = [&](float (&acc)[16], int kl) {
    float4* q = (float4*)(dst + (size_t)kl * 16);
#pragma unroll
    for (int w = 0; w < 4; ++w)
      q[w] = make_float4(acc[4 * w], acc[4 * w + 1], acc[4 * w + 2], acc[4 * w + 3]);
  };
  wr(acc0, kl0); wr(acc1, kl1); wr(acc2, kl2);
}

// ---------------- KR: partials -> raw m_i/m_j + contracted mic/mjc + quad ---
__global__ __launch_bounds__(256) void kr_reduce(
    const float* __restrict__ mi_part, const float* __restrict__ mj_part,
    const float* __restrict__ coefs2,
    float* __restrict__ mi_raw, float* __restrict__ mj_raw,
    float* __restrict__ mic, float* __restrict__ mjc,
    float* __restrict__ quad_raw) {
  const int t = threadIdx.x;
  const int pos = blockIdx.x * 256 + t;   // 110592 total
  const bool isI = pos < 55296;           // block-uniform (55296 = 216*256)
  const int p = isI ? pos : pos - 55296;
  __shared__ float cc[256];
  cc[t] = coefs2[t * 16 + (isI ? 1 : 2)];
  __syncthreads();
  const float* src = (isI ? mi_part : mj_part) + (size_t)p * 16;
  float raw[16];
#pragma unroll
  for (int s = 0; s < 16; ++s) raw[s] = 0.f;
#pragma unroll
  for (int g = 0; g < 4; ++g) {
    const float4* q = (const float4*)(src + (size_t)g * 884736);
#pragma unroll
    for (int w = 0; w < 4; ++w) {
      float4 v = q[w];
      raw[4 * w] += v.x; raw[4 * w + 1] += v.y;
      raw[4 * w + 2] += v.z; raw[4 * w + 3] += v.w;
    }
  }
  float* rdst = (isI ? mi_raw : mj_raw) + (size_t)p * 16;
#pragma unroll
  for (int w = 0; w < 4; ++w)
    ((float4*)rdst)[w] = make_float4(raw[4 * w], raw[4 * w + 1], raw[4 * w + 2], raw[4 * w + 3]);
  float o[16];
#pragma unroll
  for (int s2 = 0; s2 < 16; ++s2) {
    float v = 0.f;
#pragma unroll
    for (int s = 0; s < 16; ++s) v += cc[s * 16 + s2] * raw[s];
    o[s2] = v;
  }
  float* cdst = (isI ? mic : mjc) + (size_t)p * 16;
#pragma unroll
  for (int w = 0; w < 4; ++w)
    ((float4*)cdst)[w] = make_float4(o[4 * w], o[4 * w + 1], o[4 * w + 2], o[4 * w + 3]);
  if (isI) {  // quad marginal: wave-reduce raw, one atomic set per wave
#pragma unroll
    for (int s = 0; s < 16; ++s) {
      float v = raw[s];
      for (int off = 32; off; off >>= 1) v += __shfl_xor(v, off, 64);
      raw[s] = v;
    }
    if ((t & 63) == 0) {
      int b = p / 13824;  // b uniform per wave (13824 = 216 waves of 64)
#pragma unroll
      for (int s = 0; s < 16; ++s) atomicAdd(&quad_raw[b * 16 + s], raw[s]);
    }
  }
}

// ---------------- KD: pairs (720 blk) + triples (384 blk) + finisher --------
__global__ __launch_bounds__(256) void kd_derived(
    const float* __restrict__ mi_raw, const float* __restrict__ mj_raw,
    const float* __restrict__ quad_raw, const float* __restrict__ coefs2,
    const float* __restrict__ b_out,
    float* __restrict__ mijc, float* __restrict__ mikc, float* __restrict__ milc,
    float* __restrict__ mjkc, float* __restrict__ mjlc,
    float* __restrict__ mijkc, float* __restrict__ mijlc,
    float* __restrict__ miklc, float* __restrict__ mjklc,
    float* __restrict__ mijklc, float* __restrict__ out) {
  const int bb = blockIdx.x, t = threadIdx.x;
  __shared__ float cc[256];
  __shared__ float ex[16][17];
  __shared__ float tot[16];
  if (bb < 720) {  // pairs: 24-term sums, thread per (pos, s)
    int tbl = bb / 144;  // uniform per block
    cc[t] = coefs2[t * 16 + 5 + tbl];
    int pp = t >> 4, s = t & 15;
    int pos = (bb % 144) * 16 + pp;
    int b = pos / 576, rem = pos % 576;
    const float* srcb; int stride;
    if (tbl == 0) { srcb = mi_raw + ((size_t)b * 24 * 576 + rem) * 16 + s; stride = 576 * 16; }
    else if (tbl == 1) { int jj = rem / 24, l = rem % 24;
      srcb = mi_raw + (((size_t)(b * 24 + jj)) * 576 + l) * 16 + s; stride = 24 * 16; }
    else if (tbl == 2) { int jj = rem / 24, k = rem % 24;
      srcb = mi_raw + (((size_t)(b * 24 + jj)) * 576 + k * 24) * 16 + s; stride = 16; }
    else if (tbl == 3) { int ii = rem / 24, l = rem % 24;
      srcb = mj_raw + (((size_t)(b * 24 + ii)) * 576 + l) * 16 + s; stride = 24 * 16; }
    else { int ii = rem / 24, k = rem % 24;
      srcb = mj_raw + (((size_t)(b * 24 + ii)) * 576 + k * 24) * 16 + s; stride = 16; }
    float v = 0.f;
#pragma unroll 4
    for (int x = 0; x < 24; ++x) v += srcb[(size_t)x * stride];
    ex[pp][s] = v;
    __syncthreads();
    float o = 0.f;
#pragma unroll
    for (int ss = 0; ss < 16; ++ss) o += cc[ss * 16 + s] * ex[pp][ss];
    float* dst = (tbl == 0 ? mijc : tbl == 1 ? mikc : tbl == 2 ? milc : tbl == 3 ? mjkc : mjlc);
    dst[(size_t)pos * 16 + s] = o;
    return;
  }
  if (bb < 720 + 384) {  // triples: 576-term block reduce per (tbl,b,a)
    int idx = bb - 720;
    int tbl = idx / 96, rr = idx % 96;  // tbl uniform per block
    int b = rr / 24, a = rr % 24;
    cc[t] = coefs2[t * 16 + 11 + tbl];
    int gg = t >> 4, s = t & 15;
    const float* src = (tbl == 3 ? mj_raw : mi_raw);
    float v = 0.f;
#pragma unroll 4
    for (int m = 0; m < 36; ++m) {
      int u = gg + (m << 4);
      size_t addr;
      if (tbl == 0) { int j = u / 24, k = u % 24;        // mijk, keep l=a
        addr = (((size_t)(b * 24 + j)) * 576 + k * 24 + a) * 16 + s; }
      else if (tbl == 1) { int j = u / 24, l = u % 24;   // mijl, keep k=a
        addr = (((size_t)(b * 24 + j)) * 576 + a * 24 + l) * 16 + s; }
      else {                                             // mikl/mjkl, keep j/i=a
        addr = (((size_t)(b * 24 + a)) * 576 + u) * 16 + s; }
      v += src[addr];
    }
    ex[gg][s] = v;
    __syncthreads();
    if (t < 16) {
      float w2 = 0.f;
#pragma unroll
      for (int g2 = 0; g2 < 16; ++g2) w2 += ex[g2][t];
      tot[t] = w2;
    }
    __syncthreads();
    if (t < 16) {
      float o = 0.f;
#pragma unroll
      for (int ss = 0; ss < 16; ++ss) o += cc[ss * 16 + t] * tot[ss];
      float* dst = (tbl == 0 ? mijkc : tbl == 1 ? mijlc : tbl == 2 ? miklc : mjklc);
      dst[(size_t)(b * 24 + a) * 16 + t] = o;
    }
    return;
  }
  // finisher: quad contract + out init
  if (t < 64) {
    int b = t >> 4, s2 = t & 15;
    float o = 0.f;
#pragma unroll
    for (int s = 0; s < 16; ++s) o += coefs2[(s * 16 + s2) * 16 + 15] * quad_raw[b * 16 + s];
    mijklc[t] = o;
  }
  if (t >= 64 && t < 64 + NB) out[t - 64] = b_out[0];
}

// ---------------- K5: recompute tile + lookups + relu + pool + w_out --------
__global__ __launch_bounds__(192) void k5_final(
    const float* __restrict__ xw, const float* __restrict__ Sw,
    const float* __restrict__ coefs1, const float* __restrict__ bias1,
    const float* __restrict__ mic, const float* __restrict__ mjc,
    const float* __restrict__ mkc, const float* __restrict__ mlc,
    const float* __restrict__ mijc, const float* __restrict__ mikc,
    const float* __restrict__ milc, const float* __restrict__ mjkc,
    const float* __restrict__ mjlc, const float* __restrict__ mklc,
    const float* __restrict__ mijkc, const float* __restrict__ mijlc,
    const float* __restrict__ miklc, const float* __restrict__ mjklc,
    const float* __restrict__ mijklc,
    const float* __restrict__ coefs2, const float* __restrict__ bias2,
    const float* __restrict__ w_out, float* __restrict__ out) {
  const int orig = blockIdx.x;
  const int blk = (orig & 7) * 288 + (orig >> 3);  // XCD swizzle (2304 = 8*288)
  const int j = blk % NN, i = (blk / NN) % NN, b = blk / (NN * NN);
  const int t = threadIdx.x;
  __shared__ float sx[NN * ND];
  __shared__ float alphaT[NS][ND];
  __shared__ float tbs[ND][NS], tgs[ND][NS], tds[ND][NS];
  __shared__ float Bt[NN][20], Gt[NN][20];
  __shared__ float dconst[NS];
  __shared__ __align__(16) float c2id[NS][NO];
  __shared__ float Kt[NN][20], Lt[NN][20];
  __shared__ float cterm[NO], wl[NO];
  __shared__ float wsum[3];

  const float* xb = xw + b * NN * ND;
  for (int idx = t; idx < NN * ND; idx += 192) sx[idx] = xb[idx];
  for (int idx = t; idx < NS * NO; idx += 192)
    c2id[idx >> 4][idx & 15] = coefs2[idx * 16];  // basis 0
  for (int idx = t; idx < NN * NO; idx += 192) {
    int kk = idx >> 4, s2 = idx & 15;
    Kt[kk][s2] = mlc[(size_t)(((b * NN + i) * NN + j) * NN + kk) * NS + s2]
               + mjlc[(size_t)((b * NN + i) * NN + kk) * NS + s2]
               + milc[(size_t)((b * NN + j) * NN + kk) * NS + s2]
               + mijlc[(size_t)(b * NN + kk) * NS + s2];
    Lt[kk][s2] = mkc[(size_t)(((b * NN + i) * NN + j) * NN + kk) * NS + s2]
               + mjkc[(size_t)((b * NN + i) * NN + kk) * NS + s2]
               + mikc[(size_t)((b * NN + j) * NN + kk) * NS + s2]
               + mijkc[(size_t)(b * NN + kk) * NS + s2];
  }
  if (t < NO) {
    cterm[t] = mklc[(size_t)((b * NN + i) * NN + j) * NS + t]
             + miklc[(size_t)(b * NN + j) * NS + t]
             + mjklc[(size_t)(b * NN + i) * NS + t]
             + mijklc[(size_t)b * NS + t] + bias2[t];
    wl[t] = w_out[t];
  }
  __syncthreads();
  for (int idx = t; idx < 256; idx += 192) {
    int d = idx >> 4, s = idx & 15;
    const float* c = coefs1 + idx * 16;
    float xi = sx[i * 16 + d], xj = sx[j * 16 + d];
    float Sv = Sw[b * 16 + d];
    float S2 = Sv * Sv, S3 = S2 * Sv, S4 = S2 * S2;
    float pij = xi * xj;
    alphaT[s][d] = c[0] * pij + c[1] * Sv * xj + c[2] * Sv * xi + c[5] * S2;
    tbs[d][s] = c[4] * Sv * pij + c[9] * S2 * xi + c[7] * S2 * xj + c[12] * S3;
    tgs[d][s] = c[3] * Sv * pij + c[8] * S2 * xi + c[6] * S2 * xj + c[11] * S3;
    tds[d][s] = c[10] * S2 * pij + c[14] * S3 * xi + c[13] * S3 * xj + c[15] * S4;
  }
  __syncthreads();
  for (int idx = t; idx < NN * NS; idx += 192) {
    int k = idx >> 4, s = idx & 15;
    float sb = 0.f, sg = 0.f;
    for (int d = 0; d < 16; ++d) {
      float xv = sx[k * 16 + d];
      sb += tbs[d][s] * xv;
      sg += tgs[d][s] * xv;
    }
    Bt[k][s] = sb;
    Gt[k][s] = sg;
  }
  if (t < 16) {
    float sd = 0.f;
    for (int d = 0; d < 16; ++d) sd += tds[d][t];
    dconst[t] = sd + bias1[t];
  }
  __syncthreads();

  float p = 0.f;
#pragma unroll
  for (int it = 0; it < 3; ++it) {
    const int kl = t + 192 * it;
    const int k = kl / NN, l = kl % NN;
    const float4* pmi = (const float4*)(mic + ((size_t)(b * NN + j) * NKL + kl) * NS);
    const float4* pmj = (const float4*)(mjc + ((size_t)(b * NN + i) * NKL + kl) * NS);
    const float4* pms = (const float4*)(mijc + ((size_t)b * NKL + kl) * NS);
    float4 a0 = pmi[0], a1 = pmi[1], a2 = pmi[2], a3 = pmi[3];
    float4 b0 = pmj[0], b1 = pmj[1], b2 = pmj[2], b3 = pmj[3];
    float4 g0 = pms[0], g1 = pms[1], g2 = pms[2], g3 = pms[3];
    // recompute T1 for this element
    float P[16];
#pragma unroll
    for (int d = 0; d < 16; ++d) P[d] = sx[k * 16 + d] * sx[l * 16 + d];
    float pr[16];
#pragma unroll
    for (int s = 0; s < 16; ++s) {
      float av = dconst[s] + Bt[k][s] + Gt[l][s];
#pragma unroll
      for (int d = 0; d < 16; ++d) av += alphaT[s][d] * P[d];
      pr[s] = fmaxf(av, 0.f);
    }
    float va[16], vb[16], vg[16];
    ((float4*)va)[0] = a0; ((float4*)va)[1] = a1; ((float4*)va)[2] = a2; ((float4*)va)[3] = a3;
    ((float4*)vb)[0] = b0; ((float4*)vb)[1] = b1; ((float4*)vb)[2] = b2; ((float4*)vb)[3] = b3;
    ((float4*)vg)[0] = g0; ((float4*)vg)[1] = g1; ((float4*)vg)[2] = g2; ((float4*)vg)[3] = g3;
    float acc[16];
#pragma unroll
    for (int s2 = 0; s2 < 16; ++s2)
      acc[s2] = cterm[s2] + Kt[k][s2] + Lt[l][s2] + va[s2] + vb[s2] + vg[s2];
#pragma unroll
    for (int s = 0; s < 16; ++s) {
      float v = pr[s];
#pragma unroll
      for (int s2 = 0; s2 < 16; ++s2) acc[s2] += c2id[s][s2] * v;
    }
    float ps = 0.f;
#pragma unroll
    for (int s2 = 0; s2 < 16; ++s2) ps += wl[s2] * fmaxf(acc[s2], 0.f);
    p += ps;
  }
  for (int off = 32; off; off >>= 1) p += __shfl_down(p, off, 64);
  if ((t & 63) == 0) wsum[t >> 6] = p;
  __syncthreads();
  if (t == 0) atomicAdd(&out[b], wsum[0] + wsum[1] + wsum[2]);
}

// ---------------- launch -----------------------------------------------------
extern "C" void kernel_launch(void* const* d_in, const int* in_sizes, int n_in,
                              void* d_out, int out_size, void* d_ws, size_t ws_size,
                              hipStream_t stream) {
  (void)in_sizes; (void)n_in; (void)out_size; (void)ws_size;
  const int*   xcat   = (const int*)d_in[0];
  const float* xfeat  = (const float*)d_in[1];
  const float* embed  = (const float*)d_in[2];
  const float* coefs1 = (const float*)d_in[3];
  const float* bias1  = (const float*)d_in[4];
  const float* coefs2 = (const float*)d_in[5];
  const float* bias2  = (const float*)d_in[6];
  const float* w_out  = (const float*)d_in[7];
  const float* b_out  = (const float*)d_in[8];
  float* out = (float*)d_out;
  char* ws = (char*)d_ws;

  float* xw      = (float*)(ws + 0);          // 6144 B
  float* Sw      = (float*)(ws + 6144);       // 256 B
  float* mi_part = (float*)(ws + 8192);       // 4 x 884736 f = 14155776 B
  float* mj_part = (float*)(ws + 14163968);   // 14155776 B
  float* mi_raw  = (float*)(ws + 28319744);   // 3538944 B
  float* mj_raw  = (float*)(ws + 31858688);   // 3538944 B
  float* mic     = (float*)(ws + 35397632);   // 3538944 B
  float* mjc     = (float*)(ws + 38936576);   // 3538944 B
  float* mkc     = (float*)(ws + 42475520);   // 3538944 B
  float* mlc     = (float*)(ws + 46014464);   // 3538944 B
  float* mklc    = (float*)(ws + 49553408);   // 147456 B
  float* mijc    = (float*)(ws + 49700864);   // 147456 B
  float* mikc    = (float*)(ws + 49848320);
  float* milc    = (float*)(ws + 49995776);
  float* mjkc    = (float*)(ws + 50143232);
  float* mjlc    = (float*)(ws + 50290688);
  float* mijkc   = (float*)(ws + 50438144);   // 6144 B
  float* mijlc   = (float*)(ws + 50444288);
  float* miklc   = (float*)(ws + 50450432);
  float* mjklc   = (float*)(ws + 50456576);
  float* quad_raw= (float*)(ws + 50462720);   // 256 B
  float* mijklc  = (float*)(ws + 50462976);   // 256 B

  k0_prep<<<1, 256, 0, stream>>>(xcat, xfeat, embed, b_out, xw, Sw, out, quad_raw);
  ka_marg<<<768, 192, 0, stream>>>(xw, Sw, coefs1, bias1, coefs2,
                                   mi_part, mj_part, mkc, mlc, mklc);
  kr_reduce<<<432, 256, 0, stream>>>(mi_part, mj_part, coefs2,
                                     mi_raw, mj_raw, mic, mjc, quad_raw);
  kd_derived<<<1105, 256, 0, stream>>>(mi_raw, mj_raw, quad_raw, coefs2, b_out,
                                       mijc, mikc, milc, mjkc, mjlc,
                                       mijkc, mijlc, miklc, mjklc, mijklc, out);
  k5_final<<<2304, 192, 0, stream>>>(xw, Sw, coefs1, bias1,
                                     mic, mjc, mkc, mlc, mijc, mikc, milc,
                                     mjkc, mjlc, mklc, mijkc, mijlc, miklc,
                                     mjklc, mijklc, coefs2, bias2, w_out, out);
}

// Round 4
// 255.056 us; speedup vs baseline: 1.3337x; 1.2723x over previous
//
#include <hip/hip_runtime.h>
#include <hip/hip_bf16.h>

// Eq4Net: permutation-equivariant 4th-order set network.
// T = x^{ox4} is rank-1 per channel: layer-1 pre-activations are
//   pre[s](k,l) = sum_d A_ij[s][d]*x_k[d]*x_l[d] + Bt_ij[k][s] + Gt2_ij[l][s]
// with per-(i,j) tables precomputed ONCE (KT) into global memory.
// T1 = relu(pre) is never materialized; marginal passes (KA) and the final
// pass (K5) recompute elements in registers (3 elems/thread sharing each
// alphaT row read). k/l marginals come from register partials via width-8
// shfl reduction (no LDS tile). Layer-2 marginal terms pre-contracted with
// coefs2; final pass recombines + relu + pooled dot.

#define NB 4
#define NN 24
#define ND 16
#define NS 16
#define NO 16
#define NKL 576

typedef unsigned int u32;
typedef unsigned short u16;

__device__ __forceinline__ u16 f2bf(float f) {
  u32 u = __float_as_uint(f);
  u = (u + 0x7fffu + ((u >> 16) & 1u)) >> 16;  // RNE
  return (u16)u;
}

// ---------------- K0: x = [relu(embed[xcat]) , xfeat], S = sum_i x ----------
__global__ __launch_bounds__(256) void k0_prep(
    const int* __restrict__ xcat, const float* __restrict__ xfeat,
    const float* __restrict__ embed, const float* __restrict__ b_out,
    float* __restrict__ xw, float* __restrict__ Sw, float* __restrict__ out,
    float* __restrict__ quad_raw) {
  __shared__ float sx[NB * NN * ND];
  const int t = threadIdx.x;
  for (int idx = t; idx < NB * NN * ND; idx += 256) {
    int d = idx & (ND - 1);
    int bi = idx >> 4;
    float v;
    if (d < 15) v = fmaxf(embed[xcat[bi] * 15 + d], 0.0f);
    else        v = xfeat[bi];
    sx[idx] = v;
    xw[idx] = v;
  }
  __syncthreads();
  for (int idx = t; idx < NB * ND; idx += 256) {
    int d = idx & (ND - 1), b = idx >> 4;
    float s = 0.0f;
    for (int i = 0; i < NN; ++i) s += sx[(b * NN + i) * ND + d];
    Sw[idx] = s;
  }
  if (t < NB) out[t] = b_out[0];
  if (t < NB * NS) quad_raw[t] = 0.0f;
}

// ---------------- KT: per-(b,i,j) tables -> global (4KB/tile) ---------------
// layout per tile (1024 f32): [0..255]   A[s*16+d]
//                             [256..639] Bt[s*24+k]
//                             [640..1023] Gt2[s*24+l]  (incl. dconst+bias1)
__global__ __launch_bounds__(256) void kt_tables(
    const float* __restrict__ xw, const float* __restrict__ Sw,
    const float* __restrict__ coefs1, const float* __restrict__ bias1,
    float* __restrict__ tabs) {
  const int blk = blockIdx.x;  // (b*24+i)*24+j
  const int j = blk % NN, i = (blk / NN) % NN, b = blk / (NN * NN);
  const int t = threadIdx.x;
  __shared__ float sx[NN * ND];
  __shared__ float tb[256], tg[256], td[256];
  __shared__ float dconst[16];
  for (int idx = t; idx < NN * ND; idx += 256) sx[idx] = xw[b * 384 + idx];
  __syncthreads();
  {  // t = d*16+s
    int d = t >> 4, s = t & 15;
    const float* c = coefs1 + t * 16;
    float xi = sx[i * 16 + d], xj = sx[j * 16 + d];
    float Sv = Sw[b * 16 + d];
    float S2 = Sv * Sv, S3 = S2 * Sv, S4 = S2 * S2, pij = xi * xj;
    tabs[(size_t)blk * 1024 + s * 16 + d] =
        c[0] * pij + c[1] * Sv * xj + c[2] * Sv * xi + c[5] * S2;
    tb[t] = c[4] * Sv * pij + c[9] * S2 * xi + c[7] * S2 * xj + c[12] * S3;
    tg[t] = c[3] * Sv * pij + c[8] * S2 * xi + c[6] * S2 * xj + c[11] * S3;
    td[t] = c[10] * S2 * pij + c[14] * S3 * xi + c[13] * S3 * xj + c[15] * S4;
  }
  __syncthreads();
  if (t < 16) {
    float sd = 0.f;
    for (int d = 0; d < 16; ++d) sd += td[d * 16 + t];
    dconst[t] = sd + bias1[t];
  }
  __syncthreads();
  for (int idx = t; idx < 768; idx += 256) {
    int pos = idx >> 4, s = idx & 15;
    if (pos < NN) {          // Bt[k][s]
      float acc = 0.f;
#pragma unroll
      for (int d = 0; d < 16; ++d) acc += tb[d * 16 + s] * sx[pos * 16 + d];
      tabs[(size_t)blk * 1024 + 256 + s * 24 + pos] = acc;
    } else {                 // Gt2[l][s]
      int l = pos - NN;
      float acc = dconst[s];
#pragma unroll
      for (int d = 0; d < 16; ++d) acc += tg[d * 16 + s] * sx[l * 16 + d];
      tabs[(size_t)blk * 1024 + 640 + s * 24 + l] = acc;
    }
  }
}

// ---------------- KA: marginal passes (register eval, shfl reduce) ----------
// blocks 0..383:   isI: (b, a=j, g): loop i=g*6.. -> m_i[b][j] partial (bf16),
//                  per tile emit mkc (sum over k, keep l) + mklc.
// blocks 384..767: isJ: (b, a=i, g): loop j -> m_j partial + mlc (sum over l).
// Thread geometry: grp=t/8 (common row index: l for isI, k for isJ),
// sub=t%8, 3 elements at varying row 3*sub+{0,1,2}.
__global__ __launch_bounds__(192, 2) void ka_marg(
    const float* __restrict__ xw, const float* __restrict__ coefs2,
    const float* __restrict__ tabs,
    u32* __restrict__ mi_part, u32* __restrict__ mj_part,
    float* __restrict__ mkc, float* __restrict__ mlc, float* __restrict__ mklc) {
  const int bk = blockIdx.x;
  const bool isI = bk < 384;
  const int r = isI ? bk : bk - 384;
  const int b = r / 96;
  const int a = (r % 96) >> 2;
  const int g = r & 3;
  const int t = threadIdx.x;
  __shared__ float sx[NN * ND];
  __shared__ __align__(16) float tabL[1024];
  __shared__ float red[NN][17];
  __shared__ float totL[16];
  __shared__ float c2m[256];
  __shared__ float c2q[256];

  for (int idx = t; idx < NN * ND; idx += 192) sx[idx] = xw[b * 384 + idx];
  for (int idx = t; idx < 256; idx += 192) {
    c2m[idx] = coefs2[idx * 16 + (isI ? 3 : 4)];
    c2q[idx] = coefs2[idx * 16 + 10];
  }
  const int grp = t >> 3;
  const int sub = t & 7;
  const int vr = 3 * sub;
  const int cOff = isI ? 640 : 256;   // common row table (Gt2 for isI)
  const int vOff = isI ? 256 : 640;   // varying row table (Bt for isI)

  float P0[16], P1[16], P2[16];
#pragma unroll
  for (int d = 0; d < 16; ++d) {
    float xc = sx[grp * 16 + d];
    P0[d] = sx[vr * 16 + d] * xc;
    P1[d] = sx[(vr + 1) * 16 + d] * xc;
    P2[d] = sx[(vr + 2) * 16 + d] * xc;
  }
  float acc0[16], acc1[16], acc2[16];
#pragma unroll
  for (int s = 0; s < 16; ++s) { acc0[s] = 0.f; acc1[s] = 0.f; acc2[s] = 0.f; }

  for (int oo = g * 6; oo < g * 6 + 6; ++oo) {
    const int i = isI ? oo : a;
    const int j = isI ? a : oo;
    const int tile = (b * NN + i) * NN + j;
    __syncthreads();  // protect tabL/red/totL reuse
    for (int idx = t; idx < 256; idx += 192)
      ((float4*)tabL)[idx] = ((const float4*)(tabs + (size_t)tile * 1024))[idx];
    __syncthreads();

    float rp[16];
#pragma unroll
    for (int s = 0; s < 16; ++s) {
      float Ar[16];
      const float4* a4 = (const float4*)(tabL + s * 16);
      ((float4*)Ar)[0] = a4[0]; ((float4*)Ar)[1] = a4[1];
      ((float4*)Ar)[2] = a4[2]; ((float4*)Ar)[3] = a4[3];
      float ct = tabL[cOff + s * 24 + grp];
      float v0 = tabL[vOff + s * 24 + vr] + ct;
      float v1 = tabL[vOff + s * 24 + vr + 1] + ct;
      float v2 = tabL[vOff + s * 24 + vr + 2] + ct;
#pragma unroll
      for (int d = 0; d < 16; ++d) {
        v0 += Ar[d] * P0[d];
        v1 += Ar[d] * P1[d];
        v2 += Ar[d] * P2[d];
      }
      v0 = fmaxf(v0, 0.f); v1 = fmaxf(v1, 0.f); v2 = fmaxf(v2, 0.f);
      acc0[s] += v0; acc1[s] += v1; acc2[s] += v2;
      rp[s] = v0 + v1 + v2;
    }
    // width-8 reduce: sum over the 8 threads sharing grp (covers all 24 of
    // the varying index) -> red[grp][s]
#pragma unroll
    for (int s = 0; s < 16; ++s) {
      float v = rp[s];
      v += __shfl_down(v, 4, 8);
      v += __shfl_down(v, 2, 8);
      v += __shfl_down(v, 1, 8);
      rp[s] = v;
    }
    if (sub == 0) {
#pragma unroll
      for (int s = 0; s < 16; ++s) red[grp][s] = rp[s];
    }
    __syncthreads();
    // contract with coefs2 basis and store (isI: sum over k -> mkc[.. l];
    // isJ: sum over l -> mlc[.. k])
    float* mdst = isI ? mkc : mlc;
    for (int idx = t; idx < 384; idx += 192) {
      int pos = idx >> 4, s2 = idx & 15;
      float o = 0.f;
#pragma unroll
      for (int s = 0; s < 16; ++s) o += c2m[s * 16 + s2] * red[pos][s];
      mdst[((size_t)tile * NN + pos) * 16 + s2] = o;
    }
    if (isI && t < 16) {
      float v = 0.f;
      for (int p2 = 0; p2 < NN; ++p2) v += red[p2][t];
      totL[t] = v;
    }
    __syncthreads();
    if (isI && t < 16) {
      float o = 0.f;
#pragma unroll
      for (int s = 0; s < 16; ++s) o += c2q[s * 16 + t] * totL[s];
      mklc[(size_t)tile * 16 + t] = o;
    }
  }

  // write bf16-packed partial: element kl for c: isI (3sub+c)*24+grp ; isJ grp*24+3sub+c
  const int klA = isI ? (vr * 24 + grp) : (grp * 24 + vr);
  const int stepA = isI ? 24 : 1;
  u32* pb = (isI ? mi_part : mj_part) + (size_t)g * 442368 +
            ((size_t)(b * NN + a) * NKL) * 8;
  auto wrp = [&](float (&A)[16], int kl) {
    u32 w[8];
#pragma unroll
    for (int m = 0; m < 8; ++m)
      w[m] = (u32)f2bf(A[2 * m]) | ((u32)f2bf(A[2 * m + 1]) << 16);
    uint4* q = (uint4*)(pb + (size_t)kl * 8);
    q[0] = make_uint4(w[0], w[1], w[2], w[3]);
    q[1] = make_uint4(w[4], w[5], w[6], w[7]);
  };
  wrp(acc0, klA); wrp(acc1, klA + stepA); wrp(acc2, klA + 2 * stepA);
}

// ---------------- KR: partials -> raw m_i/m_j + contracted mic/mjc + quad ---
__global__ __launch_bounds__(256) void kr_reduce(
    const u32* __restrict__ mi_part, const u32* __restrict__ mj_part,
    const float* __restrict__ coefs2,
    float* __restrict__ mi_raw, float* __restrict__ mj_raw,
    float* __restrict__ mic, float* __restrict__ mjc,
    float* __restrict__ quad_raw) {
  const int t = threadIdx.x;
  const int pos = blockIdx.x * 256 + t;   // 110592 total
  const bool isI = pos < 55296;           // block-uniform
  const int p = isI ? pos : pos - 55296;
  __shared__ float cc[256];
  cc[t] = coefs2[t * 16 + (isI ? 1 : 2)];
  __syncthreads();
  const u32* src = (isI ? mi_part : mj_part) + (size_t)p * 8;
  float raw[16];
#pragma unroll
  for (int s = 0; s < 16; ++s) raw[s] = 0.f;
#pragma unroll
  for (int g = 0; g < 4; ++g) {
    const uint4* q = (const uint4*)(src + (size_t)g * 442368);
    uint4 q0 = q[0], q1 = q[1];
    u32 qa[8] = {q0.x, q0.y, q0.z, q0.w, q1.x, q1.y, q1.z, q1.w};
#pragma unroll
    for (int m = 0; m < 8; ++m) {
      raw[2 * m]     += __uint_as_float(qa[m] << 16);
      raw[2 * m + 1] += __uint_as_float(qa[m] & 0xffff0000u);
    }
  }
  float* rdst = (isI ? mi_raw : mj_raw) + (size_t)p * 16;
#pragma unroll
  for (int w = 0; w < 4; ++w)
    ((float4*)rdst)[w] = make_float4(raw[4 * w], raw[4 * w + 1], raw[4 * w + 2], raw[4 * w + 3]);
  float o[16];
#pragma unroll
  for (int s2 = 0; s2 < 16; ++s2) {
    float v = 0.f;
#pragma unroll
    for (int s = 0; s < 16; ++s) v += cc[s * 16 + s2] * raw[s];
    o[s2] = v;
  }
  float* cdst = (isI ? mic : mjc) + (size_t)p * 16;
#pragma unroll
  for (int w = 0; w < 4; ++w)
    ((float4*)cdst)[w] = make_float4(o[4 * w], o[4 * w + 1], o[4 * w + 2], o[4 * w + 3]);
  if (isI) {
#pragma unroll
    for (int s = 0; s < 16; ++s) {
      float v = raw[s];
      for (int off = 32; off; off >>= 1) v += __shfl_xor(v, off, 64);
      raw[s] = v;
    }
    if ((t & 63) == 0) {
      int b = p / 13824;
#pragma unroll
      for (int s = 0; s < 16; ++s) atomicAdd(&quad_raw[b * 16 + s], raw[s]);
    }
  }
}

// ---------------- KD: pairs (720 blk) + triples (384 blk) + finisher --------
__global__ __launch_bounds__(256) void kd_derived(
    const float* __restrict__ mi_raw, const float* __restrict__ mj_raw,
    const float* __restrict__ quad_raw, const float* __restrict__ coefs2,
    const float* __restrict__ b_out,
    float* __restrict__ mijc, float* __restrict__ mikc, float* __restrict__ milc,
    float* __restrict__ mjkc, float* __restrict__ mjlc,
    float* __restrict__ mijkc, float* __restrict__ mijlc,
    float* __restrict__ miklc, float* __restrict__ mjklc,
    float* __restrict__ mijklc, float* __restrict__ out) {
  const int bb = blockIdx.x, t = threadIdx.x;
  __shared__ float cc[256];
  __shared__ float ex[16][17];
  __shared__ float tot[16];
  if (bb < 720) {  // pairs: 24-term sums, thread per (pos, s)
    int tbl = bb / 144;
    cc[t] = coefs2[t * 16 + 5 + tbl];
    int pp = t >> 4, s = t & 15;
    int pos = (bb % 144) * 16 + pp;
    int b = pos / 576, rem = pos % 576;
    const float* srcb; int stride;
    if (tbl == 0) { srcb = mi_raw + ((size_t)b * 24 * 576 + rem) * 16 + s; stride = 576 * 16; }
    else if (tbl == 1) { int jj = rem / 24, l = rem % 24;
      srcb = mi_raw + (((size_t)(b * 24 + jj)) * 576 + l) * 16 + s; stride = 24 * 16; }
    else if (tbl == 2) { int jj = rem / 24, k = rem % 24;
      srcb = mi_raw + (((size_t)(b * 24 + jj)) * 576 + k * 24) * 16 + s; stride = 16; }
    else if (tbl == 3) { int ii = rem / 24, l = rem % 24;
      srcb = mj_raw + (((size_t)(b * 24 + ii)) * 576 + l) * 16 + s; stride = 24 * 16; }
    else { int ii = rem / 24, k = rem % 24;
      srcb = mj_raw + (((size_t)(b * 24 + ii)) * 576 + k * 24) * 16 + s; stride = 16; }
    float v = 0.f;
#pragma unroll 4
    for (int x = 0; x < 24; ++x) v += srcb[(size_t)x * stride];
    ex[pp][s] = v;
    __syncthreads();
    float o = 0.f;
#pragma unroll
    for (int ss = 0; ss < 16; ++ss) o += cc[ss * 16 + s] * ex[pp][ss];
    float* dst = (tbl == 0 ? mijc : tbl == 1 ? mikc : tbl == 2 ? milc : tbl == 3 ? mjkc : mjlc);
    dst[(size_t)pos * 16 + s] = o;
    return;
  }
  if (bb < 720 + 384) {  // triples: 576-term block reduce per (tbl,b,a)
    int idx = bb - 720;
    int tbl = idx / 96, rr = idx % 96;
    int b = rr / 24, a = rr % 24;
    cc[t] = coefs2[t * 16 + 11 + tbl];
    int gg = t >> 4, s = t & 15;
    const float* src = (tbl == 3 ? mj_raw : mi_raw);
    float v = 0.f;
#pragma unroll 4
    for (int m = 0; m < 36; ++m) {
      int u = gg + (m << 4);
      size_t addr;
      if (tbl == 0) { int j = u / 24, k = u % 24;
        addr = (((size_t)(b * 24 + j)) * 576 + k * 24 + a) * 16 + s; }
      else if (tbl == 1) { int j = u / 24, l = u % 24;
        addr = (((size_t)(b * 24 + j)) * 576 + a * 24 + l) * 16 + s; }
      else {
        addr = (((size_t)(b * 24 + a)) * 576 + u) * 16 + s; }
      v += src[addr];
    }
    ex[gg][s] = v;
    __syncthreads();
    if (t < 16) {
      float w2 = 0.f;
#pragma unroll
      for (int g2 = 0; g2 < 16; ++g2) w2 += ex[g2][t];
      tot[t] = w2;
    }
    __syncthreads();
    if (t < 16) {
      float o = 0.f;
#pragma unroll
      for (int ss = 0; ss < 16; ++ss) o += cc[ss * 16 + t] * tot[ss];
      float* dst = (tbl == 0 ? mijkc : tbl == 1 ? mijlc : tbl == 2 ? miklc : mjklc);
      dst[(size_t)(b * 24 + a) * 16 + t] = o;
    }
    return;
  }
  if (t < 64) {
    int b = t >> 4, s2 = t & 15;
    float o = 0.f;
#pragma unroll
    for (int s = 0; s < 16; ++s) o += coefs2[(s * 16 + s2) * 16 + 15] * quad_raw[b * 16 + s];
    mijklc[t] = o;
  }
  if (t >= 64 && t < 64 + NB) out[t - 64] = b_out[0];
}

// ---------------- K5: recompute elems + lookups + relu + pool + w_out -------
__global__ __launch_bounds__(192, 2) void k5_final(
    const float* __restrict__ xw, const float* __restrict__ tabs,
    const float* __restrict__ mic, const float* __restrict__ mjc,
    const float* __restrict__ mkc, const float* __restrict__ mlc,
    const float* __restrict__ mijc, const float* __restrict__ mikc,
    const float* __restrict__ milc, const float* __restrict__ mjkc,
    const float* __restrict__ mjlc, const float* __restrict__ mklc,
    const float* __restrict__ mijkc, const float* __restrict__ mijlc,
    const float* __restrict__ miklc, const float* __restrict__ mjklc,
    const float* __restrict__ mijklc,
    const float* __restrict__ coefs2, const float* __restrict__ bias2,
    const float* __restrict__ w_out, float* __restrict__ out) {
  const int orig = blockIdx.x;
  const int blk = (orig & 7) * 288 + (orig >> 3);  // XCD swizzle (2304 = 8*288)
  const int j = blk % NN, i = (blk / NN) % NN, b = blk / (NN * NN);
  const int t = threadIdx.x;
  __shared__ float sx[NN * ND];
  __shared__ __align__(16) float tabL[1024];
  __shared__ __align__(16) float c2id[NS][NO];
  __shared__ float Kt[NN][20], Lt[NN][20];
  __shared__ float cterm[NO], wl[NO];
  __shared__ float wsum[3];

  for (int idx = t; idx < NN * ND; idx += 192) sx[idx] = xw[b * 384 + idx];
  for (int idx = t; idx < 256; idx += 192)
    ((float4*)tabL)[idx] = ((const float4*)(tabs + (size_t)blk * 1024))[idx];
  for (int idx = t; idx < NS * NO; idx += 192)
    c2id[idx >> 4][idx & 15] = coefs2[idx * 16];  // basis 0
  for (int idx = t; idx < NN * NO; idx += 192) {
    int kk = idx >> 4, s2 = idx & 15;
    Kt[kk][s2] = mlc[(size_t)(((b * NN + i) * NN + j) * NN + kk) * NS + s2]
               + mjlc[(size_t)((b * NN + i) * NN + kk) * NS + s2]
               + milc[(size_t)((b * NN + j) * NN + kk) * NS + s2]
               + mijlc[(size_t)(b * NN + kk) * NS + s2];
    Lt[kk][s2] = mkc[(size_t)(((b * NN + i) * NN + j) * NN + kk) * NS + s2]
               + mjkc[(size_t)((b * NN + i) * NN + kk) * NS + s2]
               + mikc[(size_t)((b * NN + j) * NN + kk) * NS + s2]
               + mijkc[(size_t)(b * NN + kk) * NS + s2];
  }
  if (t < NO) {
    cterm[t] = mklc[(size_t)((b * NN + i) * NN + j) * NS + t]
             + miklc[(size_t)(b * NN + j) * NS + t]
             + mjklc[(size_t)(b * NN + i) * NS + t]
             + mijklc[(size_t)b * NS + t] + bias2[t];
    wl[t] = w_out[t];
  }
  __syncthreads();

  const int l = t % 24, kb = t / 24;  // elements (kb,l),(kb+8,l),(kb+16,l)
  float P0[16], P1[16], P2[16];
#pragma unroll
  for (int d = 0; d < 16; ++d) {
    float xl = sx[l * 16 + d];
    P0[d] = sx[kb * 16 + d] * xl;
    P1[d] = sx[(kb + 8) * 16 + d] * xl;
    P2[d] = sx[(kb + 16) * 16 + d] * xl;
  }
  float pr0[16], pr1[16], pr2[16];
#pragma unroll
  for (int s = 0; s < 16; ++s) {
    float Ar[16];
    const float4* a4 = (const float4*)(tabL + s * 16);
    ((float4*)Ar)[0] = a4[0]; ((float4*)Ar)[1] = a4[1];
    ((float4*)Ar)[2] = a4[2]; ((float4*)Ar)[3] = a4[3];
    float gt = tabL[640 + s * 24 + l];
    float v0 = tabL[256 + s * 24 + kb] + gt;
    float v1 = tabL[256 + s * 24 + kb + 8] + gt;
    float v2 = tabL[256 + s * 24 + kb + 16] + gt;
#pragma unroll
    for (int d = 0; d < 16; ++d) {
      v0 += Ar[d] * P0[d];
      v1 += Ar[d] * P1[d];
      v2 += Ar[d] * P2[d];
    }
    pr0[s] = fmaxf(v0, 0.f);
    pr1[s] = fmaxf(v1, 0.f);
    pr2[s] = fmaxf(v2, 0.f);
  }

  auto epi = [&](float (&pr)[16], int kl) -> float {
    const int k = kl / 24, ll = kl % 24;
    const float4* pmi = (const float4*)(mic + ((size_t)(b * NN + j) * NKL + kl) * 16);
    const float4* pmj = (const float4*)(mjc + ((size_t)(b * NN + i) * NKL + kl) * 16);
    const float4* pms = (const float4*)(mijc + ((size_t)b * NKL + kl) * 16);
    float acc[16];
#pragma unroll
    for (int w = 0; w < 4; ++w) {
      float4 va = pmi[w], vb = pmj[w], vg = pms[w];
      acc[4 * w + 0] = cterm[4 * w + 0] + Kt[k][4 * w + 0] + Lt[ll][4 * w + 0] + va.x + vb.x + vg.x;
      acc[4 * w + 1] = cterm[4 * w + 1] + Kt[k][4 * w + 1] + Lt[ll][4 * w + 1] + va.y + vb.y + vg.y;
      acc[4 * w + 2] = cterm[4 * w + 2] + Kt[k][4 * w + 2] + Lt[ll][4 * w + 2] + va.z + vb.z + vg.z;
      acc[4 * w + 3] = cterm[4 * w + 3] + Kt[k][4 * w + 3] + Lt[ll][4 * w + 3] + va.w + vb.w + vg.w;
    }
#pragma unroll
    for (int s = 0; s < 16; ++s) {
      float v = pr[s];
#pragma unroll
      for (int s2 = 0; s2 < 16; ++s2) acc[s2] += c2id[s][s2] * v;
    }
    float ps = 0.f;
#pragma unroll
    for (int s2 = 0; s2 < 16; ++s2) ps += wl[s2] * fmaxf(acc[s2], 0.f);
    return ps;
  };
  float p = epi(pr0, t) + epi(pr1, t + 192) + epi(pr2, t + 384);

  for (int off = 32; off; off >>= 1) p += __shfl_down(p, off, 64);
  if ((t & 63) == 0) wsum[t >> 6] = p;
  __syncthreads();
  if (t == 0) atomicAdd(&out[b], wsum[0] + wsum[1] + wsum[2]);
}

// ---------------- launch -----------------------------------------------------
extern "C" void kernel_launch(void* const* d_in, const int* in_sizes, int n_in,
                              void* d_out, int out_size, void* d_ws, size_t ws_size,
                              hipStream_t stream) {
  (void)in_sizes; (void)n_in; (void)out_size; (void)ws_size;
  const int*   xcat   = (const int*)d_in[0];
  const float* xfeat  = (const float*)d_in[1];
  const float* embed  = (const float*)d_in[2];
  const float* coefs1 = (const float*)d_in[3];
  const float* bias1  = (const float*)d_in[4];
  const float* coefs2 = (const float*)d_in[5];
  const float* bias2  = (const float*)d_in[6];
  const float* w_out  = (const float*)d_in[7];
  const float* b_out  = (const float*)d_in[8];
  float* out = (float*)d_out;
  char* ws = (char*)d_ws;

  float* xw      = (float*)(ws + 0);          // 6144 B
  float* Sw      = (float*)(ws + 6144);       // 256 B
  float* tabs    = (float*)(ws + 8192);       // 2304*1024*4 = 9437184 B
  u32*   mi_part = (u32*)(ws + 9445376);      // 4 grp * 442368 u32 = 7077888 B
  u32*   mj_part = (u32*)(ws + 16523264);     // 7077888 B
  float* mi_raw  = (float*)(ws + 23601152);   // 3538944 B
  float* mj_raw  = (float*)(ws + 27140096);
  float* mic     = (float*)(ws + 30679040);
  float* mjc     = (float*)(ws + 34217984);
  float* mkc     = (float*)(ws + 37756928);
  float* mlc     = (float*)(ws + 41295872);
  float* mklc    = (float*)(ws + 44834816);   // 147456 B
  float* mijc    = (float*)(ws + 44982272);
  float* mikc    = (float*)(ws + 45129728);
  float* milc    = (float*)(ws + 45277184);
  float* mjkc    = (float*)(ws + 45424640);
  float* mjlc    = (float*)(ws + 45572096);
  float* mijkc   = (float*)(ws + 45719552);   // 6144 B
  float* mijlc   = (float*)(ws + 45725696);
  float* miklc   = (float*)(ws + 45731840);
  float* mjklc   = (float*)(ws + 45737984);
  float* quad_raw= (float*)(ws + 45744128);   // 256 B
  float* mijklc  = (float*)(ws + 45744384);   // 256 B

  k0_prep<<<1, 256, 0, stream>>>(xcat, xfeat, embed, b_out, xw, Sw, out, quad_raw);
  kt_tables<<<NB * NN * NN, 256, 0, stream>>>(xw, Sw, coefs1, bias1, tabs);
  ka_marg<<<768, 192, 0, stream>>>(xw, coefs2, tabs, mi_part, mj_part, mkc, mlc, mklc);
  kr_reduce<<<432, 256, 0, stream>>>(mi_part, mj_part, coefs2,
                                     mi_raw, mj_raw, mic, mjc, quad_raw);
  kd_derived<<<1105, 256, 0, stream>>>(mi_raw, mj_raw, quad_raw, coefs2, b_out,
                                       mijc, mikc, milc, mjkc, mjlc,
                                       mijkc, mijlc, miklc, mjklc, mijklc, out);
  k5_final<<<2304, 192, 0, stream>>>(xw, tabs, mic, mjc, mkc, mlc,
                                     mijc, mikc, milc, mjkc, mjlc, mklc,
                                     mijkc, mijlc, miklc, mjklc, mijklc,
                                     coefs2, bias2, w_out, out);
}

// Round 5
// 172.717 us; speedup vs baseline: 1.9696x; 1.4767x over previous
//
#include <hip/hip_runtime.h>
#include <hip/hip_bf16.h>

// Eq4Net: permutation-equivariant 4th-order set network.
// T = x^{ox4} is rank-1 per channel: layer-1 pre-activations are
//   pre[s](k,l) = sum_d A_ij[s][d]*x_k[d]*x_l[d] + Bt_ij[k][s] + Gt2_ij[l][s]
// with per-(i,j) tables precomputed ONCE (KT): A bf16-packed, Bt/Gt2 in a
// padded [s][32] layout so each thread's 3 varying bases are one float4.
// T1 = relu(pre) is never materialized; marginal passes (KA) and the final
// pass (K5) recompute elements in registers. NO contended atomics anywhere:
// quad marginal via per-block partials (KR->KD), pooled output via per-block
// partials (K5->K6). Layer-2 marginal terms pre-contracted with coefs2.

#define NB 4
#define NN 24
#define ND 16
#define NS 16
#define NO 16
#define NKL 576
#define TSTRIDE 1152  // floats per tile: 128 packed-A words + 512 Bt + 512 Gt2

typedef unsigned int u32;
typedef unsigned short u16;

__device__ __forceinline__ u16 f2bf(float f) {
  u32 u = __float_as_uint(f);
  u = (u + 0x7fffu + ((u >> 16) & 1u)) >> 16;  // RNE
  return (u16)u;
}

// ---------------- K0: x = [relu(embed[xcat]) , xfeat], S = sum_i x ----------
__global__ __launch_bounds__(256) void k0_prep(
    const int* __restrict__ xcat, const float* __restrict__ xfeat,
    const float* __restrict__ embed,
    float* __restrict__ xw, float* __restrict__ Sw) {
  __shared__ float sx[NB * NN * ND];
  const int t = threadIdx.x;
  for (int idx = t; idx < NB * NN * ND; idx += 256) {
    int d = idx & (ND - 1);
    int bi = idx >> 4;
    float v;
    if (d < 15) v = fmaxf(embed[xcat[bi] * 15 + d], 0.0f);
    else        v = xfeat[bi];
    sx[idx] = v;
    xw[idx] = v;
  }
  __syncthreads();
  for (int idx = t; idx < NB * ND; idx += 256) {
    int d = idx & (ND - 1), b = idx >> 4;
    float s = 0.0f;
    for (int i = 0; i < NN; ++i) s += sx[(b * NN + i) * ND + d];
    Sw[idx] = s;
  }
}

// ---------------- KT: per-(b,i,j) tables -> global ---------------------------
// tile layout (1152 f32 slots): [0..127]   A bf16-packed (s*8+m, pair d=2m,2m+1)
//   [128..639]  Bt[s*32 + (k/3)*4 + k%3]   [640..1151] Gt2[s*32 + (l/3)*4 + l%3]
// Gt2 includes dconst+bias1. Pad slots unwritten (never read into arithmetic).
__global__ __launch_bounds__(256) void kt_tables(
    const float* __restrict__ xw, const float* __restrict__ Sw,
    const float* __restrict__ coefs1, const float* __restrict__ bias1,
    float* __restrict__ tabs) {
  const int blk = blockIdx.x;  // (b*24+i)*24+j
  const int j = blk % NN, i = (blk / NN) % NN, b = blk / (NN * NN);
  const int t = threadIdx.x;
  __shared__ float sx[NN * ND];
  __shared__ float Af[256], tb[256], tg[256], td[256];
  __shared__ float dconst[16];
  for (int idx = t; idx < NN * ND; idx += 256) sx[idx] = xw[b * 384 + idx];
  __syncthreads();
  {  // t = d*16+s
    int d = t >> 4, s = t & 15;
    const float* c = coefs1 + t * 16;
    float xi = sx[i * 16 + d], xj = sx[j * 16 + d];
    float Sv = Sw[b * 16 + d];
    float S2 = Sv * Sv, S3 = S2 * Sv, S4 = S2 * S2, pij = xi * xj;
    Af[s * 16 + d] = c[0] * pij + c[1] * Sv * xj + c[2] * Sv * xi + c[5] * S2;
    tb[t] = c[4] * Sv * pij + c[9] * S2 * xi + c[7] * S2 * xj + c[12] * S3;
    tg[t] = c[3] * Sv * pij + c[8] * S2 * xi + c[6] * S2 * xj + c[11] * S3;
    td[t] = c[10] * S2 * pij + c[14] * S3 * xi + c[13] * S3 * xj + c[15] * S4;
  }
  __syncthreads();
  if (t < 16) {
    float sd = 0.f;
    for (int d = 0; d < 16; ++d) sd += td[d * 16 + t];
    dconst[t] = sd + bias1[t];
  }
  __syncthreads();
  float* tile = tabs + (size_t)blk * TSTRIDE;
  if (t < 128) {  // pack A rows: s = t>>3, m = t&7
    int s = t >> 3, m = t & 7;
    tile[t] = __uint_as_float((u32)f2bf(Af[s * 16 + 2 * m]) |
                              ((u32)f2bf(Af[s * 16 + 2 * m + 1]) << 16));
  }
  for (int idx = t; idx < 768; idx += 256) {
    int pos = idx >> 4, s = idx & 15;
    if (pos < NN) {  // Bt[k]
      float acc = 0.f;
#pragma unroll
      for (int d = 0; d < 16; ++d) acc += tb[d * 16 + s] * sx[pos * 16 + d];
      tile[128 + s * 32 + (pos / 3) * 4 + pos % 3] = acc;
    } else {         // Gt2[l] (+dconst)
      int l = pos - NN;
      float acc = dconst[s];
#pragma unroll
      for (int d = 0; d < 16; ++d) acc += tg[d * 16 + s] * sx[l * 16 + d];
      tile[640 + s * 32 + (l / 3) * 4 + l % 3] = acc;
    }
  }
}

// ---------------- KA: marginal passes (register eval, shfl reduce) ----------
// blocks 0..383:   isI: (b, a=j, g): loop i -> m_i[b][j] partial (bf16) +
//                  per-tile contracted mkc (keep l) + mklc.
// blocks 384..767: isJ: (b, a=i, g): loop j -> m_j partial + mlc (keep k).
// grp=t>>3 (common index: l for isI, k for isJ), sub=t&7, varying = 3sub+{0,1,2}.
__global__ __launch_bounds__(192, 2) void ka_marg(
    const float* __restrict__ xw, const float* __restrict__ coefs2,
    const float* __restrict__ tabs,
    u32* __restrict__ mi_part, u32* __restrict__ mj_part,
    float* __restrict__ mkc, float* __restrict__ mlc, float* __restrict__ mklc) {
  const int bk = blockIdx.x;
  const bool isI = bk < 384;
  const int r = isI ? bk : bk - 384;
  const int b = r / 96;
  const int a = (r % 96) >> 2;
  const int g = r & 3;
  const int t = threadIdx.x;
  __shared__ float sx[NN * ND];
  __shared__ __align__(16) float tabL[TSTRIDE];
  __shared__ __align__(16) float red[NN][16];
  __shared__ float totL[16];
  __shared__ __align__(16) float c2mT[16][20];  // [s2][s], padded
  __shared__ float c2qT[256];                    // [s2*16+s]

  for (int idx = t; idx < NN * ND; idx += 192) sx[idx] = xw[b * 384 + idx];
  for (int idx = t; idx < 256; idx += 192) {
    int s = idx >> 4, s2 = idx & 15;
    c2mT[s2][s] = coefs2[idx * 16 + (isI ? 3 : 4)];
    c2qT[s2 * 16 + s] = coefs2[idx * 16 + 10];
  }
  __syncthreads();  // sx must be complete before P (cross-wave)

  const int grp = t >> 3, sub = t & 7, vr = 3 * sub;
  const int grpPos = (grp / 3) * 4 + grp % 3;
  const int cOff = isI ? 640 : 128;  // common-index table
  const int vOff = isI ? 128 : 640;  // varying-index table

  float P0[16], P1[16], P2[16];
#pragma unroll
  for (int d = 0; d < 16; ++d) {
    float xc = sx[grp * 16 + d];
    P0[d] = sx[vr * 16 + d] * xc;
    P1[d] = sx[(vr + 1) * 16 + d] * xc;
    P2[d] = sx[(vr + 2) * 16 + d] * xc;
  }
  float acc0[16], acc1[16], acc2[16];
#pragma unroll
  for (int s = 0; s < 16; ++s) { acc0[s] = 0.f; acc1[s] = 0.f; acc2[s] = 0.f; }

  for (int oo = g * 6; oo < g * 6 + 6; ++oo) {
    const int i = isI ? oo : a;
    const int j = isI ? a : oo;
    const int tile = (b * NN + i) * NN + j;
    __syncthreads();  // protect tabL/red reuse
    for (int idx = t; idx < 288; idx += 192)
      ((float4*)tabL)[idx] = ((const float4*)(tabs + (size_t)tile * TSTRIDE))[idx];
    __syncthreads();

    float rp[16];
#pragma unroll
    for (int s = 0; s < 16; ++s) {
      const uint4* ap = (const uint4*)(tabL + s * 8);
      uint4 A0 = ap[0], A1 = ap[1];
      u32 qa[8] = {A0.x, A0.y, A0.z, A0.w, A1.x, A1.y, A1.z, A1.w};
      float Afr[16];
#pragma unroll
      for (int m = 0; m < 8; ++m) {
        Afr[2 * m]     = __uint_as_float(qa[m] << 16);
        Afr[2 * m + 1] = __uint_as_float(qa[m] & 0xffff0000u);
      }
      float4 vb4 = *(const float4*)(tabL + vOff + s * 32 + sub * 4);
      float ct = tabL[cOff + s * 32 + grpPos];
      float v0 = vb4.x + ct, v1 = vb4.y + ct, v2 = vb4.z + ct;
#pragma unroll
      for (int d = 0; d < 16; ++d) {
        v0 += Afr[d] * P0[d];
        v1 += Afr[d] * P1[d];
        v2 += Afr[d] * P2[d];
      }
      v0 = fmaxf(v0, 0.f); v1 = fmaxf(v1, 0.f); v2 = fmaxf(v2, 0.f);
      acc0[s] += v0; acc1[s] += v1; acc2[s] += v2;
      rp[s] = v0 + v1 + v2;
    }
    // width-8 reduce over sub -> per-common-index sums
#pragma unroll
    for (int s = 0; s < 16; ++s) {
      float v = rp[s];
      v += __shfl_down(v, 4, 8);
      v += __shfl_down(v, 2, 8);
      v += __shfl_down(v, 1, 8);
      rp[s] = v;
    }
    if (sub == 0) {
      float4* rw = (float4*)(&red[grp][0]);
#pragma unroll
      for (int w = 0; w < 4; ++w)
        rw[w] = make_float4(rp[4 * w], rp[4 * w + 1], rp[4 * w + 2], rp[4 * w + 3]);
    }
    __syncthreads();
    // contract with coefs2 basis, store (isI: mkc keep-l; isJ: mlc keep-k)
    float* mdst = isI ? mkc : mlc;
    for (int idx = t; idx < 384; idx += 192) {
      int pos = idx >> 4, s2 = idx & 15;
      const float4* rr = (const float4*)(&red[pos][0]);
      const float4* cm = (const float4*)(&c2mT[s2][0]);
      float o = 0.f;
#pragma unroll
      for (int w = 0; w < 4; ++w) {
        float4 rv = rr[w], mv = cm[w];
        o += rv.x * mv.x + rv.y * mv.y + rv.z * mv.z + rv.w * mv.w;
      }
      mdst[((size_t)tile * NN + pos) * 16 + s2] = o;
    }
    if (isI && t < 16) {
      float v = 0.f;
      for (int aa = 0; aa < NN; ++aa) v += red[aa][t];
      totL[t] = v;
    }
    __syncthreads();
    if (isI && t < 16) {
      float o = 0.f;
#pragma unroll
      for (int s = 0; s < 16; ++s) o += c2qT[t * 16 + s] * totL[s];
      mklc[(size_t)tile * 16 + t] = o;
    }
  }

  // bf16-packed partial: element kl: isI (3sub+c)*24+grp ; isJ grp*24+3sub+c
  const int klA = isI ? (vr * NN + grp) : (grp * NN + vr);
  const int stepA = isI ? NN : 1;
  u32* pb = (isI ? mi_part : mj_part) + (size_t)g * 442368 +
            ((size_t)(b * NN + a) * NKL) * 8;
  auto wrp = [&](float (&A)[16], int kl) {
    u32 w[8];
#pragma unroll
    for (int m = 0; m < 8; ++m)
      w[m] = (u32)f2bf(A[2 * m]) | ((u32)f2bf(A[2 * m + 1]) << 16);
    uint4* q = (uint4*)(pb + (size_t)kl * 8);
    q[0] = make_uint4(w[0], w[1], w[2], w[3]);
    q[1] = make_uint4(w[4], w[5], w[6], w[7]);
  };
  wrp(acc0, klA); wrp(acc1, klA + stepA); wrp(acc2, klA + 2 * stepA);
}

// ---------------- KR: partials -> raw + contracted + quad block-partials ----
__global__ __launch_bounds__(256) void kr_reduce(
    const u32* __restrict__ mi_part, const u32* __restrict__ mj_part,
    const float* __restrict__ coefs2,
    float* __restrict__ mi_raw, float* __restrict__ mj_raw,
    float* __restrict__ mic, float* __restrict__ mjc,
    float* __restrict__ quad_part) {
  const int t = threadIdx.x;
  const int bb = blockIdx.x;
  const int pos = bb * 256 + t;      // 110592 total
  const bool isI = pos < 55296;      // block-uniform (216 blocks isI)
  const int p = isI ? pos : pos - 55296;
  __shared__ __align__(16) float ccT[16][20];  // [s2][s]
  __shared__ float qred[4][16];
  {
    int s = t >> 4, s2 = t & 15;
    ccT[s2][s] = coefs2[t * 16 + (isI ? 1 : 2)];
  }
  __syncthreads();
  const u32* src = (isI ? mi_part : mj_part) + (size_t)p * 8;
  float raw[16];
#pragma unroll
  for (int s = 0; s < 16; ++s) raw[s] = 0.f;
#pragma unroll
  for (int g = 0; g < 4; ++g) {
    const uint4* q = (const uint4*)(src + (size_t)g * 442368);
    uint4 q0 = q[0], q1 = q[1];
    u32 qa[8] = {q0.x, q0.y, q0.z, q0.w, q1.x, q1.y, q1.z, q1.w};
#pragma unroll
    for (int m = 0; m < 8; ++m) {
      raw[2 * m]     += __uint_as_float(qa[m] << 16);
      raw[2 * m + 1] += __uint_as_float(qa[m] & 0xffff0000u);
    }
  }
  float* rdst = (isI ? mi_raw : mj_raw) + (size_t)p * 16;
#pragma unroll
  for (int w = 0; w < 4; ++w)
    ((float4*)rdst)[w] = make_float4(raw[4 * w], raw[4 * w + 1], raw[4 * w + 2], raw[4 * w + 3]);
  float o[16];
#pragma unroll
  for (int s2 = 0; s2 < 16; ++s2) {
    const float4* cm = (const float4*)(&ccT[s2][0]);
    float v = 0.f;
#pragma unroll
    for (int w = 0; w < 4; ++w) {
      float4 mv = cm[w];
      v += mv.x * raw[4 * w] + mv.y * raw[4 * w + 1] + mv.z * raw[4 * w + 2] + mv.w * raw[4 * w + 3];
    }
    o[s2] = v;
  }
  float* cdst = (isI ? mic : mjc) + (size_t)p * 16;
#pragma unroll
  for (int w = 0; w < 4; ++w)
    ((float4*)cdst)[w] = make_float4(o[4 * w], o[4 * w + 1], o[4 * w + 2], o[4 * w + 3]);
  // quad marginal: block partial, NO global atomics
  if (isI) {
#pragma unroll
    for (int s = 0; s < 16; ++s) {
      float v = raw[s];
      for (int off = 32; off; off >>= 1) v += __shfl_xor(v, off, 64);
      raw[s] = v;
    }
    if ((t & 63) == 0) {
      int w = t >> 6;
#pragma unroll
      for (int s = 0; s < 16; ++s) qred[w][s] = raw[s];
    }
  }
  __syncthreads();
  if (isI && t < 16)
    quad_part[bb * 16 + t] = qred[0][t] + qred[1][t] + qred[2][t] + qred[3][t];
}

// ---------------- KD: pairs (720) + triples (384) + quad finisher -----------
__global__ __launch_bounds__(256) void kd_derived(
    const float* __restrict__ mi_raw, const float* __restrict__ mj_raw,
    const float* __restrict__ quad_part, const float* __restrict__ coefs2,
    float* __restrict__ mijc, float* __restrict__ mikc, float* __restrict__ milc,
    float* __restrict__ mjkc, float* __restrict__ mjlc,
    float* __restrict__ mijkc, float* __restrict__ mijlc,
    float* __restrict__ miklc, float* __restrict__ mjklc,
    float* __restrict__ mijklc) {
  const int bb = blockIdx.x, t = threadIdx.x;
  __shared__ float cc[256];
  __shared__ float ex[16][17];
  __shared__ float tot[16];
  __shared__ float qr[64];
  if (bb < 720) {  // pairs: 24-term sums, thread per (pos, s)
    int tbl = bb / 144;
    cc[t] = coefs2[t * 16 + 5 + tbl];
    int pp = t >> 4, s = t & 15;
    int pos = (bb % 144) * 16 + pp;
    int b = pos / 576, rem = pos % 576;
    const float* srcb; int stride;
    if (tbl == 0) { srcb = mi_raw + ((size_t)b * 24 * 576 + rem) * 16 + s; stride = 576 * 16; }
    else if (tbl == 1) { int jj = rem / 24, l = rem % 24;
      srcb = mi_raw + (((size_t)(b * 24 + jj)) * 576 + l) * 16 + s; stride = 24 * 16; }
    else if (tbl == 2) { int jj = rem / 24, k = rem % 24;
      srcb = mi_raw + (((size_t)(b * 24 + jj)) * 576 + k * 24) * 16 + s; stride = 16; }
    else if (tbl == 3) { int ii = rem / 24, l = rem % 24;
      srcb = mj_raw + (((size_t)(b * 24 + ii)) * 576 + l) * 16 + s; stride = 24 * 16; }
    else { int ii = rem / 24, k = rem % 24;
      srcb = mj_raw + (((size_t)(b * 24 + ii)) * 576 + k * 24) * 16 + s; stride = 16; }
    float v = 0.f;
#pragma unroll 4
    for (int x = 0; x < 24; ++x) v += srcb[(size_t)x * stride];
    ex[pp][s] = v;
    __syncthreads();
    float o = 0.f;
#pragma unroll
    for (int ss = 0; ss < 16; ++ss) o += cc[ss * 16 + s] * ex[pp][ss];
    float* dst = (tbl == 0 ? mijc : tbl == 1 ? mikc : tbl == 2 ? milc : tbl == 3 ? mjkc : mjlc);
    dst[(size_t)pos * 16 + s] = o;
    return;
  }
  if (bb < 720 + 384) {  // triples: 576-term block reduce per (tbl,b,a)
    int idx = bb - 720;
    int tbl = idx / 96, rr = idx % 96;
    int b = rr / 24, a = rr % 24;
    cc[t] = coefs2[t * 16 + 11 + tbl];
    int gg = t >> 4, s = t & 15;
    const float* src = (tbl == 3 ? mj_raw : mi_raw);
    float v = 0.f;
#pragma unroll 4
    for (int m = 0; m < 36; ++m) {
      int u = gg + (m << 4);
      size_t addr;
      if (tbl == 0) { int j = u / 24, k = u % 24;
        addr = (((size_t)(b * 24 + j)) * 576 + k * 24 + a) * 16 + s; }
      else if (tbl == 1) { int j = u / 24, l = u % 24;
        addr = (((size_t)(b * 24 + j)) * 576 + a * 24 + l) * 16 + s; }
      else {
        addr = (((size_t)(b * 24 + a)) * 576 + u) * 16 + s; }
      v += src[addr];
    }
    ex[gg][s] = v;
    __syncthreads();
    if (t < 16) {
      float w2 = 0.f;
#pragma unroll
      for (int g2 = 0; g2 < 16; ++g2) w2 += ex[g2][t];
      tot[t] = w2;
    }
    __syncthreads();
    if (t < 16) {
      float o = 0.f;
#pragma unroll
      for (int ss = 0; ss < 16; ++ss) o += cc[ss * 16 + t] * tot[ss];
      float* dst = (tbl == 0 ? mijkc : tbl == 1 ? mijlc : tbl == 2 ? miklc : mjklc);
      dst[(size_t)(b * 24 + a) * 16 + t] = o;
    }
    return;
  }
  // quad finisher: sum 54 block-partials per b, contract basis 15
  if (t < 64) {
    int b = t >> 4, s = t & 15;
    float v = 0.f;
    for (int c = 0; c < 54; ++c) v += quad_part[(b * 54 + c) * 16 + s];
    qr[t] = v;
  }
  __syncthreads();
  if (t < 64) {
    int b = t >> 4, s2 = t & 15;
    float o = 0.f;
#pragma unroll
    for (int s = 0; s < 16; ++s) o += coefs2[(s * 16 + s2) * 16 + 15] * qr[b * 16 + s];
    mijklc[t] = o;
  }
}

// ---------------- K5: recompute elems + lookups + relu + pool ---------------
__global__ __launch_bounds__(192, 2) void k5_final(
    const float* __restrict__ xw, const float* __restrict__ tabs,
    const float* __restrict__ mic, const float* __restrict__ mjc,
    const float* __restrict__ mkc, const float* __restrict__ mlc,
    const float* __restrict__ mijc, const float* __restrict__ mikc,
    const float* __restrict__ milc, const float* __restrict__ mjkc,
    const float* __restrict__ mjlc, const float* __restrict__ mklc,
    const float* __restrict__ mijkc, const float* __restrict__ mijlc,
    const float* __restrict__ miklc, const float* __restrict__ mjklc,
    const float* __restrict__ mijklc,
    const float* __restrict__ coefs2, const float* __restrict__ bias2,
    const float* __restrict__ w_out, float* __restrict__ pool_part) {
  const int orig = blockIdx.x;
  const int blk = (orig & 7) * 288 + (orig >> 3);  // XCD swizzle (2304 = 8*288)
  const int j = blk % NN, i = (blk / NN) % NN, b = blk / (NN * NN);
  const int t = threadIdx.x;
  __shared__ float sx[NN * ND];
  __shared__ __align__(16) float tabL[TSTRIDE];
  __shared__ __align__(16) u32 c2p[128];           // bf16-packed basis-0 rows
  __shared__ __align__(16) float Kt[NN][16], Lt[NN][16];
  __shared__ __align__(16) float cterm[16], wl[16];
  __shared__ float wsum[3];

  for (int idx = t; idx < NN * ND; idx += 192) sx[idx] = xw[b * 384 + idx];
  for (int idx = t; idx < 288; idx += 192)
    ((float4*)tabL)[idx] = ((const float4*)(tabs + (size_t)blk * TSTRIDE))[idx];
  if (t < 128) {
    int s = t >> 3, m = t & 7;
    c2p[t] = (u32)f2bf(coefs2[(s * 16 + 2 * m) * 16]) |
             ((u32)f2bf(coefs2[(s * 16 + 2 * m + 1) * 16]) << 16);
  }
  for (int idx = t; idx < NN * NO; idx += 192) {
    int kk = idx >> 4, s2 = idx & 15;
    Kt[kk][s2] = mlc[(size_t)(((b * NN + i) * NN + j) * NN + kk) * NS + s2]
               + mjlc[(size_t)((b * NN + i) * NN + kk) * NS + s2]
               + milc[(size_t)((b * NN + j) * NN + kk) * NS + s2]
               + mijlc[(size_t)(b * NN + kk) * NS + s2];
    Lt[kk][s2] = mkc[(size_t)(((b * NN + i) * NN + j) * NN + kk) * NS + s2]
               + mjkc[(size_t)((b * NN + i) * NN + kk) * NS + s2]
               + mikc[(size_t)((b * NN + j) * NN + kk) * NS + s2]
               + mijkc[(size_t)(b * NN + kk) * NS + s2];
  }
  if (t < NO) {
    cterm[t] = mklc[(size_t)((b * NN + i) * NN + j) * NS + t]
             + miklc[(size_t)(b * NN + j) * NS + t]
             + mjklc[(size_t)(b * NN + i) * NS + t]
             + mijklc[(size_t)b * NS + t] + bias2[t];
    wl[t] = w_out[t];
  }
  __syncthreads();

  const int grp = t >> 3, sub = t & 7, vr = 3 * sub;  // l = grp, k = vr+c
  const int grpPos = (grp / 3) * 4 + grp % 3;
  float P0[16], P1[16], P2[16];
#pragma unroll
  for (int d = 0; d < 16; ++d) {
    float xl = sx[grp * 16 + d];
    P0[d] = sx[vr * 16 + d] * xl;
    P1[d] = sx[(vr + 1) * 16 + d] * xl;
    P2[d] = sx[(vr + 2) * 16 + d] * xl;
  }
  float pr0[16], pr1[16], pr2[16];
#pragma unroll
  for (int s = 0; s < 16; ++s) {
    const uint4* ap = (const uint4*)(tabL + s * 8);
    uint4 A0 = ap[0], A1 = ap[1];
    u32 qa[8] = {A0.x, A0.y, A0.z, A0.w, A1.x, A1.y, A1.z, A1.w};
    float Afr[16];
#pragma unroll
    for (int m = 0; m < 8; ++m) {
      Afr[2 * m]     = __uint_as_float(qa[m] << 16);
      Afr[2 * m + 1] = __uint_as_float(qa[m] & 0xffff0000u);
    }
    float4 vb4 = *(const float4*)(tabL + 128 + s * 32 + sub * 4);
    float ct = tabL[640 + s * 32 + grpPos];
    float v0 = vb4.x + ct, v1 = vb4.y + ct, v2 = vb4.z + ct;
#pragma unroll
    for (int d = 0; d < 16; ++d) {
      v0 += Afr[d] * P0[d];
      v1 += Afr[d] * P1[d];
      v2 += Afr[d] * P2[d];
    }
    pr0[s] = fmaxf(v0, 0.f);
    pr1[s] = fmaxf(v1, 0.f);
    pr2[s] = fmaxf(v2, 0.f);
  }

  // epilogue accumulators: base (cterm+Kt+Lt) + pre-contracted big lookups
  float Ltr[16], ctr[16];
#pragma unroll
  for (int w = 0; w < 4; ++w) {
    float4 lv = ((const float4*)(&Lt[grp][0]))[w];
    float4 cv = ((const float4*)(&cterm[0]))[w];
    Ltr[4 * w] = lv.x; Ltr[4 * w + 1] = lv.y; Ltr[4 * w + 2] = lv.z; Ltr[4 * w + 3] = lv.w;
    ctr[4 * w] = cv.x; ctr[4 * w + 1] = cv.y; ctr[4 * w + 2] = cv.z; ctr[4 * w + 3] = cv.w;
  }
  float acc0[16], acc1[16], acc2[16];
  auto initElem = [&](int c, float (&acc)[16]) {
    const int kl = (vr + c) * NN + grp;
    const float4* pmi = (const float4*)(mic + ((size_t)(b * NN + j) * NKL + kl) * 16);
    const float4* pmj = (const float4*)(mjc + ((size_t)(b * NN + i) * NKL + kl) * 16);
    const float4* pms = (const float4*)(mijc + ((size_t)b * NKL + kl) * 16);
#pragma unroll
    for (int w = 0; w < 4; ++w) {
      float4 kt4 = ((const float4*)(&Kt[vr + c][0]))[w];
      float4 va = pmi[w], vb = pmj[w], vg = pms[w];
      acc[4 * w + 0] = ctr[4 * w + 0] + Ltr[4 * w + 0] + kt4.x + va.x + vb.x + vg.x;
      acc[4 * w + 1] = ctr[4 * w + 1] + Ltr[4 * w + 1] + kt4.y + va.y + vb.y + vg.y;
      acc[4 * w + 2] = ctr[4 * w + 2] + Ltr[4 * w + 2] + kt4.z + va.z + vb.z + vg.z;
      acc[4 * w + 3] = ctr[4 * w + 3] + Ltr[4 * w + 3] + kt4.w + va.w + vb.w + vg.w;
    }
  };
  initElem(0, acc0); initElem(1, acc1); initElem(2, acc2);

  // identity term: acc_c[s2] += sum_s c2id[s][s2] * pr_c[s] (row amortized x3)
#pragma unroll
  for (int s = 0; s < 16; ++s) {
    const uint4* cp = (const uint4*)(c2p + s * 8);
    uint4 C0 = cp[0], C1 = cp[1];
    u32 ca[8] = {C0.x, C0.y, C0.z, C0.w, C1.x, C1.y, C1.z, C1.w};
    float row[16];
#pragma unroll
    for (int m = 0; m < 8; ++m) {
      row[2 * m]     = __uint_as_float(ca[m] << 16);
      row[2 * m + 1] = __uint_as_float(ca[m] & 0xffff0000u);
    }
    float v0 = pr0[s], v1 = pr1[s], v2 = pr2[s];
#pragma unroll
    for (int s2 = 0; s2 < 16; ++s2) {
      acc0[s2] += row[s2] * v0;
      acc1[s2] += row[s2] * v1;
      acc2[s2] += row[s2] * v2;
    }
  }
  float p = 0.f;
#pragma unroll
  for (int s2 = 0; s2 < 16; ++s2)
    p += wl[s2] * (fmaxf(acc0[s2], 0.f) + fmaxf(acc1[s2], 0.f) + fmaxf(acc2[s2], 0.f));
  for (int off = 32; off; off >>= 1) p += __shfl_down(p, off, 64);
  if ((t & 63) == 0) wsum[t >> 6] = p;
  __syncthreads();
  if (t == 0) pool_part[blk] = wsum[0] + wsum[1] + wsum[2];
}

// ---------------- K6: pooled partials -> out (no atomics) -------------------
__global__ __launch_bounds__(256) void k6_out(
    const float* __restrict__ pool_part, const float* __restrict__ b_out,
    float* __restrict__ out) {
  const int t = threadIdx.x;
  const int b = t >> 6, lane = t & 63;
  float v = 0.f;
  for (int c = lane; c < 576; c += 64) v += pool_part[b * 576 + c];
  for (int off = 32; off; off >>= 1) v += __shfl_down(v, off, 64);
  if (lane == 0) out[b] = v + b_out[0];
}

// ---------------- launch -----------------------------------------------------
extern "C" void kernel_launch(void* const* d_in, const int* in_sizes, int n_in,
                              void* d_out, int out_size, void* d_ws, size_t ws_size,
                              hipStream_t stream) {
  (void)in_sizes; (void)n_in; (void)out_size; (void)ws_size;
  const int*   xcat   = (const int*)d_in[0];
  const float* xfeat  = (const float*)d_in[1];
  const float* embed  = (const float*)d_in[2];
  const float* coefs1 = (const float*)d_in[3];
  const float* bias1  = (const float*)d_in[4];
  const float* coefs2 = (const float*)d_in[5];
  const float* bias2  = (const float*)d_in[6];
  const float* w_out  = (const float*)d_in[7];
  const float* b_out  = (const float*)d_in[8];
  float* out = (float*)d_out;
  char* ws = (char*)d_ws;

  float* xw       = (float*)(ws + 0);          // 6144 B
  float* Sw       = (float*)(ws + 6144);       // 256 B
  float* tabs     = (float*)(ws + 8192);       // 2304*1152*4 = 10616832 B
  u32*   mi_part  = (u32*)(ws + 10625024);     // 7077888 B
  u32*   mj_part  = (u32*)(ws + 17702912);     // 7077888 B
  float* mi_raw   = (float*)(ws + 24780800);   // 3538944 B
  float* mj_raw   = (float*)(ws + 28319744);
  float* mic      = (float*)(ws + 31858688);
  float* mjc      = (float*)(ws + 35397632);
  float* mkc      = (float*)(ws + 38936576);
  float* mlc      = (float*)(ws + 42475520);
  float* mklc     = (float*)(ws + 46014464);   // 147456 B
  float* mijc     = (float*)(ws + 46161920);
  float* mikc     = (float*)(ws + 46309376);
  float* milc     = (float*)(ws + 46456832);
  float* mjkc     = (float*)(ws + 46604288);
  float* mjlc     = (float*)(ws + 46751744);
  float* mijkc    = (float*)(ws + 46899200);   // 6144 B
  float* mijlc    = (float*)(ws + 46905344);
  float* miklc    = (float*)(ws + 46911488);
  float* mjklc    = (float*)(ws + 46917632);
  float* mijklc   = (float*)(ws + 46923776);   // 256 B
  float* quad_part= (float*)(ws + 46924032);   // 13824 B
  float* pool_part= (float*)(ws + 46937856);   // 9216 B

  k0_prep<<<1, 256, 0, stream>>>(xcat, xfeat, embed, xw, Sw);
  kt_tables<<<NB * NN * NN, 256, 0, stream>>>(xw, Sw, coefs1, bias1, tabs);
  ka_marg<<<768, 192, 0, stream>>>(xw, coefs2, tabs, mi_part, mj_part, mkc, mlc, mklc);
  kr_reduce<<<432, 256, 0, stream>>>(mi_part, mj_part, coefs2,
                                     mi_raw, mj_raw, mic, mjc, quad_part);
  kd_derived<<<1105, 256, 0, stream>>>(mi_raw, mj_raw, quad_part, coefs2,
                                       mijc, mikc, milc, mjkc, mjlc,
                                       mijkc, mijlc, miklc, mjklc, mijklc);
  k5_final<<<2304, 192, 0, stream>>>(xw, tabs, mic, mjc, mkc, mlc,
                                     mijc, mikc, milc, mjkc, mjlc, mklc,
                                     mijkc, mijlc, miklc, mjklc, mijklc,
                                     coefs2, bias2, w_out, pool_part);
  k6_out<<<1, 256, 0, stream>>>(pool_part, b_out, out);
}